// Round 1
// 205.273 us; speedup vs baseline: 1.0008x; 1.0008x over previous
//
#include <hip/hip_runtime.h>

// Problem constants
#define BB    4
#define CIN   256
#define NPIX  4096     // 64*64
#define COUT  512
#define KD    256      // KEY_DIM = VAL_DIM
#define HEADS 8
#define NQ    1024     // 32*32
#define NK    4096
#define EPSV  1e-5f
// 1/sqrt(32) * log2(e): scores come out in base-2 so attn uses v_exp_f32
// directly (no v_mul per element).
#define QSCALE (0.17677669529663687f * 1.4426950408889634f)

using short8 = __attribute__((ext_vector_type(8))) short;
using f32x4  = __attribute__((ext_vector_type(4))) float;

__device__ __forceinline__ float b2f(unsigned u){ return __uint_as_float(u << 16); }
__device__ __forceinline__ unsigned short f2b(float f){
  unsigned u = __float_as_uint(f);
  return (unsigned short)((u + 0x7fffu + ((u >> 16) & 1u)) >> 16);  // RNE
}
__device__ __forceinline__ float bnrelu(float xv, float inv, float mu, float bt){
  return fmaxf((xv - mu) * inv + bt, 0.0f);
}
// pack two fp32 -> bf16x2 (round-half-up): 2 add + 1 v_perm
__device__ __forceinline__ unsigned pkbf(float lo, float hi){
  unsigned a = __float_as_uint(lo) + 0x8000u;
  unsigned b = __float_as_uint(hi) + 0x8000u;
  return __builtin_amdgcn_perm(b, a, 0x07060302u);  // [hi16(b)|hi16(a)]
}
// pack two fp32 -> bf16x2 via single HW instruction (RNE)
__device__ __forceinline__ unsigned cvtpk(float lo, float hi){
  unsigned r;
  asm("v_cvt_pk_bf16_f32 %0, %1, %2" : "=v"(r) : "v"(lo), "v"(hi));
  return r;
}

// ---------------------------------------------------------------------------
// prep_h: bn+relu(x) fp32 [b][c][pix] -> bf16 h_t [b][pix][c] (LDS transpose)
// ---------------------------------------------------------------------------
__global__ __launch_bounds__(256) void prep_h(
    const float* __restrict__ x, const float* __restrict__ gam,
    const float* __restrict__ bet, const float* __restrict__ mea,
    const float* __restrict__ var, unsigned short* __restrict__ h_t){
  __shared__ unsigned short T[64][264];
  const int b = blockIdx.y;
  const int pix0 = blockIdx.x * 64;
  const int t = threadIdx.x;
  const int w = t >> 6, lane = t & 63;
  for (int cc = 0; cc < 32; ++cc){
    int c0 = cc * 8 + w * 2;
    float i0 = gam[c0]   * rsqrtf(var[c0]   + EPSV), mu0 = mea[c0],   bt0 = bet[c0];
    float i1 = gam[c0+1] * rsqrtf(var[c0+1] + EPSV), mu1 = mea[c0+1], bt1 = bet[c0+1];
    float v0 = bnrelu(x[((size_t)(b*CIN + c0  ))*NPIX + pix0 + lane], i0, mu0, bt0);
    float v1 = bnrelu(x[((size_t)(b*CIN + c0+1))*NPIX + pix0 + lane], i1, mu1, bt1);
    *(unsigned*)&T[lane][c0] = pkbf(v0, v1);
  }
  __syncthreads();
  int p = t >> 2;
  unsigned short* dst = h_t + ((size_t)b * NPIX + pix0 + p) * CIN;
  #pragma unroll
  for (int i = 0; i < 8; ++i){
    int coff = i * 32 + (t & 3) * 8;
    *(uint4*)(dst + coff) = *(const uint4*)&T[p][coff];
  }
}

// ---------------------------------------------------------------------------
// prep_w v3: Wf = [512][2560] fused A: cols [0,2304) = wsh tap-major
// (k' = tap*256+ci), cols [2304,2560) = wo. Then wq(*QSCALE)|wk|wv flat.
// ---------------------------------------------------------------------------
#define WF_K  2560
#define WF_E  (512*2560)
__global__ __launch_bounds__(256) void prep_w3(
    const float* __restrict__ wsh, const float* __restrict__ wq,
    const float* __restrict__ wk,  const float* __restrict__ wv,
    const float* __restrict__ wo,  unsigned short* __restrict__ W2){
  const int blk = blockIdx.x;
  const int t = threadIdx.x;
  if (blk < 512){
    __shared__ float R[2304];
    const float* src = wsh + (size_t)blk * 2304;
    #pragma unroll
    for (int i = 0; i < 9; ++i) R[i * 256 + t] = src[i * 256 + t];
    __syncthreads();
    unsigned short* dst = W2 + (size_t)blk * WF_K;
    #pragma unroll
    for (int i = 0; i < 9; ++i){
      int kp = i * 256 + t;                  // k' = tap*256 + ci
      int tap = kp >> 8, ci = kp & 255;
      dst[kp] = f2b(R[ci * 9 + tap]);
    }
  } else if (blk < 704){
    int idx = (blk - 512) * 1024 + t * 4;    // [0, 196608)
    float4 v;
    if (idx < 65536){
      v = *(const float4*)(wq + idx);
      v.x *= QSCALE; v.y *= QSCALE; v.z *= QSCALE; v.w *= QSCALE;
    } else if (idx < 2*65536){ v = *(const float4*)(wk + idx - 65536);
    } else {                   v = *(const float4*)(wv + idx - 2*65536); }
    uint2 pk;
    pk.x = (unsigned)f2b(v.x) | ((unsigned)f2b(v.y) << 16);
    pk.y = (unsigned)f2b(v.z) | ((unsigned)f2b(v.w) << 16);
    *(uint2*)(W2 + WF_E + idx) = pk;
  } else {
    int idx = (blk - 704) * 1024 + t * 4;    // [0, 131072) over wo
    int m = idx >> 8, c = idx & 255;
    float4 v = *(const float4*)(wo + idx);
    uint2 pk;
    pk.x = (unsigned)f2b(v.x) | ((unsigned)f2b(v.y) << 16);
    pk.y = (unsigned)f2b(v.z) | ((unsigned)f2b(v.w) << 16);
    *(uint2*)(W2 + (size_t)m * WF_K + 2304 + c) = pk;
  }
}

// ---------------------------------------------------------------------------
// KV GEMM (merged, prefetched, ALL 4 BATCHES): A = [wk2;wv2] [512][256];
// BM=64 BN=128 BK=32. y<4 -> K rows (normal, ktg [b*8+h][n][32]); y>=4 ->
// V rows (swapped) into BLOCKED V^T: vtg [b*8+h][kchunk(128)][d(32)][k32(32)].
// Grid (32,8,4) = 1024 blocks = 4/CU.
// ---------------------------------------------------------------------------
__global__ __launch_bounds__(256) void kv_gemm(
    const unsigned short* __restrict__ Wkv,
    const unsigned short* __restrict__ h_t,
    unsigned short* __restrict__ ktg,
    unsigned short* __restrict__ vtg){
  const int b  = blockIdx.z;
  const int m0 = blockIdx.y * 64;
  const bool isv = m0 >= 256;
  const int n0 = blockIdx.x * 128;
  const int t  = threadIdx.x;
  const int w = t >> 6, lane = t & 63, col = lane & 15, quad = lane >> 4;
  const int wm = w & 1, wn = w >> 1;
  __shared__ unsigned short As[64][40];
  __shared__ unsigned short Bs[128][40];
  f32x4 acc[2][4];
  #pragma unroll
  for (int i = 0; i < 2; ++i)
    #pragma unroll
    for (int j = 0; j < 4; ++j) acc[i][j] = (f32x4){0.f,0.f,0.f,0.f};
  const int am = t >> 2, ak = (t & 3) * 8;
  const int bn = t >> 1, bkh = (t & 1) * 16;
  const size_t browbase = ((size_t)b * NPIX + (n0 + bn)) * CIN;

  uint4 av  = *(const uint4*)(Wkv + (size_t)(m0 + am) * 256 + ak);
  uint4 bv0 = *(const uint4*)(h_t + browbase + bkh);
  uint4 bv1 = *(const uint4*)(h_t + browbase + bkh + 8);

  for (int k0 = 0; k0 < 256; k0 += 32){
    *(uint4*)&As[am][ak]      = av;
    *(uint4*)&Bs[bn][bkh]     = bv0;
    *(uint4*)&Bs[bn][bkh + 8] = bv1;
    __syncthreads();
    if (k0 + 32 < 256){                       // prefetch next chunk
      av  = *(const uint4*)(Wkv + (size_t)(m0 + am) * 256 + k0 + 32 + ak);
      bv0 = *(const uint4*)(h_t + browbase + k0 + 32 + bkh);
      bv1 = *(const uint4*)(h_t + browbase + k0 + 32 + bkh + 8);
    }
    short8 af[2], bf[4];
    af[0] = *(const short8*)&As[wm * 32 +      col][quad * 8];
    af[1] = *(const short8*)&As[wm * 32 + 16 + col][quad * 8];
    #pragma unroll
    for (int j = 0; j < 4; ++j)
      bf[j] = *(const short8*)&Bs[wn * 64 + j * 16 + col][quad * 8];
    if (!isv){
      #pragma unroll
      for (int i = 0; i < 2; ++i)
        #pragma unroll
        for (int j = 0; j < 4; ++j)
          acc[i][j] = __builtin_amdgcn_mfma_f32_16x16x32_bf16(af[i], bf[j], acc[i][j], 0, 0, 0);
    } else {
      #pragma unroll
      for (int i = 0; i < 2; ++i)
        #pragma unroll
        for (int j = 0; j < 4; ++j)
          acc[i][j] = __builtin_amdgcn_mfma_f32_16x16x32_bf16(bf[j], af[i], acc[i][j], 0, 0, 0);
    }
    __syncthreads();
  }

  if (!isv){
    int head = (m0 + wm * 32) >> 5;
    #pragma unroll
    for (int i = 0; i < 2; ++i){
      int d0 = i * 16 + quad * 4;
      #pragma unroll
      for (int j = 0; j < 4; ++j){
        int n = n0 + wn * 64 + j * 16 + col;
        uint2 pk;
        pk.x = pkbf(acc[i][j][0], acc[i][j][1]);
        pk.y = pkbf(acc[i][j][2], acc[i][j][3]);
        *(uint2*)(ktg + ((size_t)(b * HEADS + head) * NK + n) * 32 + d0) = pk;
      }
    }
  } else {
    int head = ((m0 - 256) + wm * 32) >> 5;
    #pragma unroll
    for (int i = 0; i < 2; ++i){
      int d = i * 16 + col;
      #pragma unroll
      for (int j = 0; j < 4; ++j){
        int nb = n0 + wn * 64 + j * 16 + quad * 4;
        size_t addr = (((size_t)(b * HEADS + head) * 128 + (nb >> 5)) * 32 + d) * 32 + (nb & 31);
        uint2 pk;
        pk.x = pkbf(acc[i][j][0], acc[i][j][1]);
        pk.y = pkbf(acc[i][j][2], acc[i][j][3]);
        *(uint2*)(vtg + addr) = pk;
      }
    }
  }
}

// ---------------------------------------------------------------------------
// q GEMM: 64x64 tile, BK=32, prefetched. normal orient, pix = stride2(n).
// ---------------------------------------------------------------------------
__global__ __launch_bounds__(256) void q_gemm(
    const unsigned short* __restrict__ Wq,    // [256][256]
    const unsigned short* __restrict__ h_t,
    unsigned short* __restrict__ qt){
  const int b  = blockIdx.z;
  const int m0 = blockIdx.y * 64;
  const int n0 = blockIdx.x * 64;
  const int t  = threadIdx.x;
  const int w = t >> 6, lane = t & 63, col = lane & 15, quad = lane >> 4;
  const int wm = w & 1, wn = w >> 1;
  __shared__ unsigned short As[64][40];
  __shared__ unsigned short Bs[64][40];
  f32x4 acc[2][2];
  #pragma unroll
  for (int i = 0; i < 2; ++i)
    #pragma unroll
    for (int j = 0; j < 2; ++j) acc[i][j] = (f32x4){0.f,0.f,0.f,0.f};
  const int am = t >> 2, ak = (t & 3) * 8;
  const int bn = t >> 2, bk = (t & 3) * 8;
  int n = n0 + bn;
  const size_t browbase = ((size_t)b * NPIX + (((n >> 5) << 7) + ((n & 31) << 1))) * CIN;

  uint4 av = *(const uint4*)(Wq + (size_t)(m0 + am) * 256 + ak);
  uint4 bv = *(const uint4*)(h_t + browbase + bk);

  for (int k0 = 0; k0 < 256; k0 += 32){
    *(uint4*)&As[am][ak] = av;
    *(uint4*)&Bs[bn][bk] = bv;
    __syncthreads();
    if (k0 + 32 < 256){
      av = *(const uint4*)(Wq + (size_t)(m0 + am) * 256 + k0 + 32 + ak);
      bv = *(const uint4*)(h_t + browbase + k0 + 32 + bk);
    }
    short8 af[2], bf[2];
    af[0] = *(const short8*)&As[wm * 32 +      col][quad * 8];
    af[1] = *(const short8*)&As[wm * 32 + 16 + col][quad * 8];
    bf[0] = *(const short8*)&Bs[wn * 32 +      col][quad * 8];
    bf[1] = *(const short8*)&Bs[wn * 32 + 16 + col][quad * 8];
    #pragma unroll
    for (int i = 0; i < 2; ++i)
      #pragma unroll
      for (int j = 0; j < 2; ++j)
        acc[i][j] = __builtin_amdgcn_mfma_f32_16x16x32_bf16(af[i], bf[j], acc[i][j], 0, 0, 0);
    __syncthreads();
  }

  int head = (m0 + wm * 32) >> 5;
  #pragma unroll
  for (int i = 0; i < 2; ++i){
    int d0 = i * 16 + quad * 4;
    #pragma unroll
    for (int j = 0; j < 2; ++j){
      int nn = n0 + wn * 32 + j * 16 + col;
      uint2 pk;
      pk.x = pkbf(acc[i][j][0], acc[i][j][1]);
      pk.y = pkbf(acc[i][j][2], acc[i][j][3]);
      *(uint2*)(qt + ((size_t)(b * HEADS + head) * NQ + nn) * 32 + d0) = pk;
    }
  }
}

// ---------------------------------------------------------------------------
// Fused shortcut+wo GEMM, 64x64 tiles (512 blocks = 2/CU).
// C[b][512][1024] = Wf · [im2col(h_t); aot], K = 2304 + 256. fp32 out.
// ---------------------------------------------------------------------------
__global__ __launch_bounds__(256) void scwo_gemm(
    const unsigned short* __restrict__ Wf,    // [512][2560]
    const unsigned short* __restrict__ h_t,
    const unsigned short* __restrict__ aot,   // [b][1024][256]
    float* __restrict__ outf){
  const int b  = blockIdx.z;
  const int m0 = blockIdx.y * 64;
  const int n0 = blockIdx.x * 64;
  const int t  = threadIdx.x;
  const int w = t >> 6, lane = t & 63, col = lane & 15, quad = lane >> 4;
  const int wm = w & 1, wn = w >> 1;
  __shared__ unsigned short As[64][40];
  __shared__ unsigned short Bs[64][40];
  f32x4 acc[2][2];
  #pragma unroll
  for (int i = 0; i < 2; ++i)
    #pragma unroll
    for (int j = 0; j < 2; ++j) acc[i][j] = (f32x4){0.f,0.f,0.f,0.f};
  const int am = t >> 2, ak = (t & 3) * 8;
  const int bn = t >> 2, bk = (t & 3) * 8;
  const int n = n0 + bn;
  const int oy = n >> 5, ox = n & 31;
  const size_t aobase = ((size_t)b * NQ + n) * KD;

  auto loadB = [&](int k0) -> uint4 {
    if (k0 < 2304){
      int tap = k0 >> 8;                     // uniform per chunk
      int ky = tap / 3, kx = tap - ky * 3;
      int iy = 2 * oy + ky - 1, ix = 2 * ox + kx - 1;
      if (((unsigned)iy < 64u) && ((unsigned)ix < 64u))
        return *(const uint4*)(h_t + ((size_t)b * NPIX + iy * 64 + ix) * CIN + (k0 & 255) + bk);
      return make_uint4(0,0,0,0);            // conv zero-pad
    }
    return *(const uint4*)(aot + aobase + (k0 - 2304) + bk);
  };

  uint4 av = *(const uint4*)(Wf + (size_t)(m0 + am) * WF_K + ak);
  uint4 bv = loadB(0);

  for (int k0 = 0; k0 < WF_K; k0 += 32){
    *(uint4*)&As[am][ak] = av;
    *(uint4*)&Bs[bn][bk] = bv;
    __syncthreads();
    if (k0 + 32 < WF_K){
      av = *(const uint4*)(Wf + (size_t)(m0 + am) * WF_K + k0 + 32 + ak);
      bv = loadB(k0 + 32);
    }
    short8 af[2], bf[2];
    af[0] = *(const short8*)&As[wm * 32 +      col][quad * 8];
    af[1] = *(const short8*)&As[wm * 32 + 16 + col][quad * 8];
    bf[0] = *(const short8*)&Bs[wn * 32 +      col][quad * 8];
    bf[1] = *(const short8*)&Bs[wn * 32 + 16 + col][quad * 8];
    #pragma unroll
    for (int i = 0; i < 2; ++i)
      #pragma unroll
      for (int j = 0; j < 2; ++j)
        acc[i][j] = __builtin_amdgcn_mfma_f32_16x16x32_bf16(bf[j], af[i], acc[i][j], 0, 0, 0);
    __syncthreads();
  }

  #pragma unroll
  for (int i = 0; i < 2; ++i){
    int co = m0 + wm * 32 + i * 16 + col;
    #pragma unroll
    for (int j = 0; j < 2; ++j){
      int nb = n0 + wn * 32 + j * 16 + quad * 4;
      float4 o;
      o.x = acc[i][j][0]; o.y = acc[i][j][1];
      o.z = acc[i][j][2]; o.w = acc[i][j][3];
      *(float4*)(outf + ((size_t)(b * COUT + co)) * NQ + nb) = o;
    }
  }
}

// ---------------------------------------------------------------------------
// MFMA flash attention v9 = v8 with the softmax transform rebuilt:
//  - scores arrive pre-multiplied by log2(e) (folded into QSCALE) so
//    P = v_exp_f32(S) directly (exp2), no per-element v_mul;
//  - f32->bf16 pack via v_cvt_pk_bf16_f32 (1 op vs 3);
//  - C-layout -> B-operand layout via 2x v_permlane32_swap_b32 +
//    2x v_permlane16_swap_b32 (full-rate VALU) instead of 8 ds_bpermute
//    + 4 cndmask (kills the 4.39M SQ_LDS_BANK_CONFLICT cycles).
// Layout proof: lane (q=lane&15, quad t) holds X0/X1 = slo keys
// (4t+0,1)/(4t+2,3), Y0/Y1 = shi keys 16+(4t+0,1)/(4t+2,3).
// permlane32_swap(X,Y): A=[X@q01|Y@q01], B=[X@q23|Y@q23];
// permlane16_swap(A,B): A'=[X@q0|X@q2|Y@q0|Y@q2] = T(+0,1)-word,
// B'=[X@q1|X@q3|Y@q1|Y@q3] = T(+4,5)-word => pf = {x0,x1,y0,y1} is the
// B-operand fragment (k = quad*8+j, n = lane&15). 2048 blocks = 8/CU.
// ---------------------------------------------------------------------------
__global__ __launch_bounds__(256) void attn8(
    const unsigned short* __restrict__ qt,    // [b*8+hd][1024][32] (pre-scaled)
    const unsigned short* __restrict__ ktg,   // [bh][4096][32]
    const unsigned short* __restrict__ vtg,   // [bh][128][32][32] blocked V^T
    unsigned short* __restrict__ aot){        // [b][1024][256]
  __shared__ float Om4[4][64][8];
  __shared__ float Ll4[4][64];
  const int bid = blockIdx.x;
  const int xcd = bid & 7, slot = bid >> 3;
  const int bh = xcd * 4 + (slot >> 6);       // 4 bh per XCD
  const int qblk = slot & 63;
  const int b = bh >> 3, hd = bh & 7;
  const int t = threadIdx.x;
  const int w = t >> 6, lane = t & 63, col = lane & 15, quad = lane >> 4;
  const int q = qblk * 16 + col;

  short8 qf = *(const short8*)(qt + ((size_t)bh * NQ + q) * 32 + quad * 8);
  const unsigned short* kb = ktg + (size_t)bh * NK * 32;
  const unsigned short* vb = vtg + (size_t)bh * 128 * 1024;
  const int ks = w * 1024, ke = ks + 1024;

  short8 kf0 = *(const short8*)(kb + (size_t)(ks +      col) * 32 + quad * 8);
  short8 kf1 = *(const short8*)(kb + (size_t)(ks + 16 + col) * 32 + quad * 8);
  short8 vf0 = *(const short8*)(vb + ((ks >> 5) << 10) +       col * 32 + quad * 8);
  short8 vf1 = *(const short8*)(vb + ((ks >> 5) << 10) + 512 + col * 32 + quad * 8);

  f32x4 O0 = {0.f,0.f,0.f,0.f}, O1 = {0.f,0.f,0.f,0.f}, l4 = {0.f,0.f,0.f,0.f};
  const short8 ones = {0x3F80,0x3F80,0x3F80,0x3F80,0x3F80,0x3F80,0x3F80,0x3F80};

  for (int k0 = ks; k0 < ke; k0 += 32){
    int kn = (k0 + 32 < ke) ? (k0 + 32) : ks;   // wrapped prefetch (no OOB)
    int cn = (kn >> 5) << 10;
    short8 nk0 = *(const short8*)(kb + (size_t)(kn +      col) * 32 + quad * 8);
    short8 nk1 = *(const short8*)(kb + (size_t)(kn + 16 + col) * 32 + quad * 8);
    short8 nv0 = *(const short8*)(vb + cn +       col * 32 + quad * 8);
    short8 nv1 = *(const short8*)(vb + cn + 512 + col * 32 + quad * 8);

    f32x4 z = {0.f,0.f,0.f,0.f};
    f32x4 slo = __builtin_amdgcn_mfma_f32_16x16x32_bf16(kf0, qf, z, 0, 0, 0);
    f32x4 shi = __builtin_amdgcn_mfma_f32_16x16x32_bf16(kf1, qf, z, 0, 0, 0);

    // P = 2^S (log2e pre-folded), packed to bf16 pairs
    unsigned x0 = cvtpk(__builtin_amdgcn_exp2f(slo[0]), __builtin_amdgcn_exp2f(slo[1]));
    unsigned x1 = cvtpk(__builtin_amdgcn_exp2f(slo[2]), __builtin_amdgcn_exp2f(slo[3]));
    unsigned y0 = cvtpk(__builtin_amdgcn_exp2f(shi[0]), __builtin_amdgcn_exp2f(shi[1]));
    unsigned y1 = cvtpk(__builtin_amdgcn_exp2f(shi[2]), __builtin_amdgcn_exp2f(shi[3]));

    // C-layout -> B-operand layout, pure VALU cross-lane (no LDS, no fences)
    asm("v_permlane32_swap_b32 %0, %1" : "+v"(x0), "+v"(y0));
    asm("v_permlane32_swap_b32 %0, %1" : "+v"(x1), "+v"(y1));
    asm("v_permlane16_swap_b32 %0, %1" : "+v"(x0), "+v"(y0));
    asm("v_permlane16_swap_b32 %0, %1" : "+v"(x1), "+v"(y1));
    unsigned f[4] = {x0, x1, y0, y1};
    short8 pf;
    memcpy(&pf, f, 16);

    O0 = __builtin_amdgcn_mfma_f32_16x16x32_bf16(vf0, pf, O0, 0, 0, 0);
    O1 = __builtin_amdgcn_mfma_f32_16x16x32_bf16(vf1, pf, O1, 0, 0, 0);
    l4 = __builtin_amdgcn_mfma_f32_16x16x32_bf16(ones, pf, l4, 0, 0, 0);
    kf0 = nk0; kf1 = nk1; vf0 = nv0; vf1 = nv1;
  }

  // 4-partial merge: plain sums (no-max softmax => no rescale needed)
  Ll4[w][lane] = l4[0];
  *(f32x4*)&Om4[w][lane][0] = O0;
  *(f32x4*)&Om4[w][lane][4] = O1;
  __syncthreads();
  if (w == 0){
    float L = l4[0] + Ll4[1][lane] + Ll4[2][lane] + Ll4[3][lane];
    float o[8];
    #pragma unroll
    for (int j = 0; j < 8; ++j)
      o[j] = Om4[0][lane][j] + Om4[1][lane][j] + Om4[2][lane][j] + Om4[3][lane][j];
    float inv = 1.0f / L;
    unsigned short* dst = aot + ((size_t)(b * NQ + q)) * KD + hd * 32;
    uint2 pk;
    pk.x = pkbf(o[0] * inv, o[1] * inv);
    pk.y = pkbf(o[2] * inv, o[3] * inv);
    *(uint2*)(dst + quad * 4) = pk;
    pk.x = pkbf(o[4] * inv, o[5] * inv);
    pk.y = pkbf(o[6] * inv, o[7] * inv);
    *(uint2*)(dst + 16 + quad * 4) = pk;
  }
}

// ---------------------------------------------------------------------------
extern "C" void kernel_launch(void* const* d_in, const int* in_sizes, int n_in,
                              void* d_out, int out_size, void* d_ws, size_t ws_size,
                              hipStream_t stream){
  const float* x   = (const float*)d_in[0];
  const float* bg  = (const float*)d_in[1];
  const float* bbt = (const float*)d_in[2];
  const float* bm  = (const float*)d_in[3];
  const float* bv  = (const float*)d_in[4];
  const float* wsh = (const float*)d_in[5];
  const float* wq  = (const float*)d_in[6];
  const float* wk  = (const float*)d_in[7];
  const float* wvv = (const float*)d_in[8];
  const float* wo  = (const float*)d_in[9];
  float* out = (float*)d_out;                 // fp32 output

  // workspace (bf16), full 4-batch K/V: 32.4 MB
  unsigned short* h_t = (unsigned short*)d_ws;                 // 4*4096*256
  unsigned short* W2  = h_t + (size_t)BB * NPIX * CIN;         // 1,507,328
  unsigned short* qt  = W2  + (WF_E + 3*65536);                // 4*8*1024*32
  unsigned short* aot = qt  + (size_t)BB * HEADS * NQ * 32;    // 4*1024*256
  unsigned short* ktg = aot + (size_t)BB * NQ * KD;            // 4*8*4096*32
  unsigned short* vtg = ktg + (size_t)BB * HEADS * NK * 32;    // 4*8*128*1024
  size_t need = ((size_t)(vtg + (size_t)BB * HEADS * 32 * NK - h_t)) * 2;
  if (ws_size < need) return;

  unsigned short* Wf   = W2;                   // [512][2560] = wsh|wo fused
  unsigned short* wq2  = W2 + WF_E;
  unsigned short* wkv2 = wq2 + 65536;          // [wk2;wv2] = [512][256]

  prep_h<<<dim3(64, 4), dim3(256), 0, stream>>>(x, bg, bbt, bm, bv, h_t);
  prep_w3<<<dim3(832), dim3(256), 0, stream>>>(wsh, wq, wk, wvv, wo, W2);
  q_gemm<<<dim3(16, 4, 4), dim3(256), 0, stream>>>(wq2, h_t, qt);
  kv_gemm<<<dim3(32, 8, 4), dim3(256), 0, stream>>>(wkv2, h_t, ktg, vtg);
  attn8<<<dim3(2048), dim3(256), 0, stream>>>(qt, ktg, vtg, aot);
  scwo_gemm<<<dim3(16, 8, 4), dim3(256), 0, stream>>>(Wf, h_t, aot, out);
}

// Round 3
// 175.634 us; speedup vs baseline: 1.1697x; 1.1688x over previous
//
#include <hip/hip_runtime.h>

// Problem constants
#define BB    4
#define CIN   256
#define NPIX  4096     // 64*64
#define COUT  512
#define KD    256      // KEY_DIM = VAL_DIM
#define HEADS 8
#define NQ    1024     // 32*32
#define NK    4096
#define EPSV  1e-5f
// 1/sqrt(32) * log2(e): scores come out in base-2 so attn uses v_exp_f32
// directly (no v_mul per element).
#define QSCALE (0.17677669529663687f * 1.4426950408889634f)

using short8 = __attribute__((ext_vector_type(8))) short;
using f32x4  = __attribute__((ext_vector_type(4))) float;

__device__ __forceinline__ float b2f(unsigned u){ return __uint_as_float(u << 16); }
__device__ __forceinline__ unsigned short f2b(float f){
  unsigned u = __float_as_uint(f);
  return (unsigned short)((u + 0x7fffu + ((u >> 16) & 1u)) >> 16);  // RNE
}
__device__ __forceinline__ float bnrelu(float xv, float inv, float mu, float bt){
  return fmaxf((xv - mu) * inv + bt, 0.0f);
}
// pack two fp32 -> bf16x2 (round-half-up): 2 add + 1 v_perm
__device__ __forceinline__ unsigned pkbf(float lo, float hi){
  unsigned a = __float_as_uint(lo) + 0x8000u;
  unsigned b = __float_as_uint(hi) + 0x8000u;
  return __builtin_amdgcn_perm(b, a, 0x07060302u);  // [hi16(b)|hi16(a)]
}
// pack two fp32 -> bf16x2 via single HW instruction (RNE)
__device__ __forceinline__ unsigned cvtpk(float lo, float hi){
  unsigned r;
  asm("v_cvt_pk_bf16_f32 %0, %1, %2" : "=v"(r) : "v"(lo), "v"(hi));
  return r;
}

// ---------------------------------------------------------------------------
// prep_h: bn+relu(x) fp32 [b][c][pix] -> bf16 h_t [b][pix][c] (LDS transpose)
// ---------------------------------------------------------------------------
__global__ __launch_bounds__(256) void prep_h(
    const float* __restrict__ x, const float* __restrict__ gam,
    const float* __restrict__ bet, const float* __restrict__ mea,
    const float* __restrict__ var, unsigned short* __restrict__ h_t){
  __shared__ unsigned short T[64][264];
  const int b = blockIdx.y;
  const int pix0 = blockIdx.x * 64;
  const int t = threadIdx.x;
  const int w = t >> 6, lane = t & 63;
  for (int cc = 0; cc < 32; ++cc){
    int c0 = cc * 8 + w * 2;
    float i0 = gam[c0]   * rsqrtf(var[c0]   + EPSV), mu0 = mea[c0],   bt0 = bet[c0];
    float i1 = gam[c0+1] * rsqrtf(var[c0+1] + EPSV), mu1 = mea[c0+1], bt1 = bet[c0+1];
    float v0 = bnrelu(x[((size_t)(b*CIN + c0  ))*NPIX + pix0 + lane], i0, mu0, bt0);
    float v1 = bnrelu(x[((size_t)(b*CIN + c0+1))*NPIX + pix0 + lane], i1, mu1, bt1);
    *(unsigned*)&T[lane][c0] = pkbf(v0, v1);
  }
  __syncthreads();
  int p = t >> 2;
  unsigned short* dst = h_t + ((size_t)b * NPIX + pix0 + p) * CIN;
  #pragma unroll
  for (int i = 0; i < 8; ++i){
    int coff = i * 32 + (t & 3) * 8;
    *(uint4*)(dst + coff) = *(const uint4*)&T[p][coff];
  }
}

// ---------------------------------------------------------------------------
// prep_w v3: Wf = [512][2560] fused A: cols [0,2304) = wsh tap-major
// (k' = tap*256+ci), cols [2304,2560) = wo. Then wq(*QSCALE)|wk|wv flat.
// ---------------------------------------------------------------------------
#define WF_K  2560
#define WF_E  (512*2560)
__global__ __launch_bounds__(256) void prep_w3(
    const float* __restrict__ wsh, const float* __restrict__ wq,
    const float* __restrict__ wk,  const float* __restrict__ wv,
    const float* __restrict__ wo,  unsigned short* __restrict__ W2){
  const int blk = blockIdx.x;
  const int t = threadIdx.x;
  if (blk < 512){
    __shared__ float R[2304];
    const float* src = wsh + (size_t)blk * 2304;
    #pragma unroll
    for (int i = 0; i < 9; ++i) R[i * 256 + t] = src[i * 256 + t];
    __syncthreads();
    unsigned short* dst = W2 + (size_t)blk * WF_K;
    #pragma unroll
    for (int i = 0; i < 9; ++i){
      int kp = i * 256 + t;                  // k' = tap*256 + ci
      int tap = kp >> 8, ci = kp & 255;
      dst[kp] = f2b(R[ci * 9 + tap]);
    }
  } else if (blk < 704){
    int idx = (blk - 512) * 1024 + t * 4;    // [0, 196608)
    float4 v;
    if (idx < 65536){
      v = *(const float4*)(wq + idx);
      v.x *= QSCALE; v.y *= QSCALE; v.z *= QSCALE; v.w *= QSCALE;
    } else if (idx < 2*65536){ v = *(const float4*)(wk + idx - 65536);
    } else {                   v = *(const float4*)(wv + idx - 2*65536); }
    uint2 pk;
    pk.x = (unsigned)f2b(v.x) | ((unsigned)f2b(v.y) << 16);
    pk.y = (unsigned)f2b(v.z) | ((unsigned)f2b(v.w) << 16);
    *(uint2*)(W2 + WF_E + idx) = pk;
  } else {
    int idx = (blk - 704) * 1024 + t * 4;    // [0, 131072) over wo
    int m = idx >> 8, c = idx & 255;
    float4 v = *(const float4*)(wo + idx);
    uint2 pk;
    pk.x = (unsigned)f2b(v.x) | ((unsigned)f2b(v.y) << 16);
    pk.y = (unsigned)f2b(v.z) | ((unsigned)f2b(v.w) << 16);
    *(uint2*)(W2 + (size_t)m * WF_K + 2304 + c) = pk;
  }
}

// ---------------------------------------------------------------------------
// KV GEMM (merged, prefetched, ALL 4 BATCHES): A = [wk2;wv2] [512][256];
// BM=64 BN=128 BK=32. y<4 -> K rows (normal, ktg [b*8+h][n][32]); y>=4 ->
// V rows (swapped) into BLOCKED V^T: vtg [b*8+h][kchunk(128)][d(32)][k32(32)].
// Grid (32,8,4) = 1024 blocks = 4/CU.  (round-1 verified version, unchanged)
// ---------------------------------------------------------------------------
__global__ __launch_bounds__(256) void kv_gemm(
    const unsigned short* __restrict__ Wkv,
    const unsigned short* __restrict__ h_t,
    unsigned short* __restrict__ ktg,
    unsigned short* __restrict__ vtg){
  const int b  = blockIdx.z;
  const int m0 = blockIdx.y * 64;
  const bool isv = m0 >= 256;
  const int n0 = blockIdx.x * 128;
  const int t  = threadIdx.x;
  const int w = t >> 6, lane = t & 63, col = lane & 15, quad = lane >> 4;
  const int wm = w & 1, wn = w >> 1;
  __shared__ unsigned short As[64][40];
  __shared__ unsigned short Bs[128][40];
  f32x4 acc[2][4];
  #pragma unroll
  for (int i = 0; i < 2; ++i)
    #pragma unroll
    for (int j = 0; j < 4; ++j) acc[i][j] = (f32x4){0.f,0.f,0.f,0.f};
  const int am = t >> 2, ak = (t & 3) * 8;
  const int bn = t >> 1, bkh = (t & 1) * 16;
  const size_t browbase = ((size_t)b * NPIX + (n0 + bn)) * CIN;

  uint4 av  = *(const uint4*)(Wkv + (size_t)(m0 + am) * 256 + ak);
  uint4 bv0 = *(const uint4*)(h_t + browbase + bkh);
  uint4 bv1 = *(const uint4*)(h_t + browbase + bkh + 8);

  for (int k0 = 0; k0 < 256; k0 += 32){
    *(uint4*)&As[am][ak]      = av;
    *(uint4*)&Bs[bn][bkh]     = bv0;
    *(uint4*)&Bs[bn][bkh + 8] = bv1;
    __syncthreads();
    if (k0 + 32 < 256){                       // prefetch next chunk
      av  = *(const uint4*)(Wkv + (size_t)(m0 + am) * 256 + k0 + 32 + ak);
      bv0 = *(const uint4*)(h_t + browbase + k0 + 32 + bkh);
      bv1 = *(const uint4*)(h_t + browbase + k0 + 32 + bkh + 8);
    }
    short8 af[2], bf[4];
    af[0] = *(const short8*)&As[wm * 32 +      col][quad * 8];
    af[1] = *(const short8*)&As[wm * 32 + 16 + col][quad * 8];
    #pragma unroll
    for (int j = 0; j < 4; ++j)
      bf[j] = *(const short8*)&Bs[wn * 64 + j * 16 + col][quad * 8];
    if (!isv){
      #pragma unroll
      for (int i = 0; i < 2; ++i)
        #pragma unroll
        for (int j = 0; j < 4; ++j)
          acc[i][j] = __builtin_amdgcn_mfma_f32_16x16x32_bf16(af[i], bf[j], acc[i][j], 0, 0, 0);
    } else {
      #pragma unroll
      for (int i = 0; i < 2; ++i)
        #pragma unroll
        for (int j = 0; j < 4; ++j)
          acc[i][j] = __builtin_amdgcn_mfma_f32_16x16x32_bf16(bf[j], af[i], acc[i][j], 0, 0, 0);
    }
    __syncthreads();
  }

  if (!isv){
    int head = (m0 + wm * 32) >> 5;
    #pragma unroll
    for (int i = 0; i < 2; ++i){
      int d0 = i * 16 + quad * 4;
      #pragma unroll
      for (int j = 0; j < 4; ++j){
        int n = n0 + wn * 64 + j * 16 + col;
        uint2 pk;
        pk.x = pkbf(acc[i][j][0], acc[i][j][1]);
        pk.y = pkbf(acc[i][j][2], acc[i][j][3]);
        *(uint2*)(ktg + ((size_t)(b * HEADS + head) * NK + n) * 32 + d0) = pk;
      }
    }
  } else {
    int head = ((m0 - 256) + wm * 32) >> 5;
    #pragma unroll
    for (int i = 0; i < 2; ++i){
      int d = i * 16 + col;
      #pragma unroll
      for (int j = 0; j < 4; ++j){
        int nb = n0 + wn * 64 + j * 16 + quad * 4;
        size_t addr = (((size_t)(b * HEADS + head) * 128 + (nb >> 5)) * 32 + d) * 32 + (nb & 31);
        uint2 pk;
        pk.x = pkbf(acc[i][j][0], acc[i][j][1]);
        pk.y = pkbf(acc[i][j][2], acc[i][j][3]);
        *(uint2*)(vtg + addr) = pk;
      }
    }
  }
}

// ---------------------------------------------------------------------------
// q GEMM: 64x64 tile, BK=32, prefetched. normal orient, pix = stride2(n).
// ---------------------------------------------------------------------------
__global__ __launch_bounds__(256) void q_gemm(
    const unsigned short* __restrict__ Wq,    // [256][256]
    const unsigned short* __restrict__ h_t,
    unsigned short* __restrict__ qt){
  const int b  = blockIdx.z;
  const int m0 = blockIdx.y * 64;
  const int n0 = blockIdx.x * 64;
  const int t  = threadIdx.x;
  const int w = t >> 6, lane = t & 63, col = lane & 15, quad = lane >> 4;
  const int wm = w & 1, wn = w >> 1;
  __shared__ unsigned short As[64][40];
  __shared__ unsigned short Bs[64][40];
  f32x4 acc[2][2];
  #pragma unroll
  for (int i = 0; i < 2; ++i)
    #pragma unroll
    for (int j = 0; j < 2; ++j) acc[i][j] = (f32x4){0.f,0.f,0.f,0.f};
  const int am = t >> 2, ak = (t & 3) * 8;
  const int bn = t >> 2, bk = (t & 3) * 8;
  int n = n0 + bn;
  const size_t browbase = ((size_t)b * NPIX + (((n >> 5) << 7) + ((n & 31) << 1))) * CIN;

  uint4 av = *(const uint4*)(Wq + (size_t)(m0 + am) * 256 + ak);
  uint4 bv = *(const uint4*)(h_t + browbase + bk);

  for (int k0 = 0; k0 < 256; k0 += 32){
    *(uint4*)&As[am][ak] = av;
    *(uint4*)&Bs[bn][bk] = bv;
    __syncthreads();
    if (k0 + 32 < 256){
      av = *(const uint4*)(Wq + (size_t)(m0 + am) * 256 + k0 + 32 + ak);
      bv = *(const uint4*)(h_t + browbase + k0 + 32 + bk);
    }
    short8 af[2], bf[2];
    af[0] = *(const short8*)&As[wm * 32 +      col][quad * 8];
    af[1] = *(const short8*)&As[wm * 32 + 16 + col][quad * 8];
    bf[0] = *(const short8*)&Bs[wn * 32 +      col][quad * 8];
    bf[1] = *(const short8*)&Bs[wn * 32 + 16 + col][quad * 8];
    #pragma unroll
    for (int i = 0; i < 2; ++i)
      #pragma unroll
      for (int j = 0; j < 2; ++j)
        acc[i][j] = __builtin_amdgcn_mfma_f32_16x16x32_bf16(af[i], bf[j], acc[i][j], 0, 0, 0);
    __syncthreads();
  }

  int head = (m0 + wm * 32) >> 5;
  #pragma unroll
  for (int i = 0; i < 2; ++i){
    int d0 = i * 16 + quad * 4;
    #pragma unroll
    for (int j = 0; j < 2; ++j){
      int nn = n0 + wn * 32 + j * 16 + col;
      uint2 pk;
      pk.x = pkbf(acc[i][j][0], acc[i][j][1]);
      pk.y = pkbf(acc[i][j][2], acc[i][j][3]);
      *(uint2*)(qt + ((size_t)(b * HEADS + head) * NQ + nn) * 32 + d0) = pk;
    }
  }
}

// ---------------------------------------------------------------------------
// Fused shortcut+wo GEMM, 64x64 tiles (512 blocks = 2/CU).
// C[b][512][1024] = Wf · [im2col(h_t); aot], K = 2304 + 256. fp32 out.
// ---------------------------------------------------------------------------
__global__ __launch_bounds__(256) void scwo_gemm(
    const unsigned short* __restrict__ Wf,    // [512][2560]
    const unsigned short* __restrict__ h_t,
    const unsigned short* __restrict__ aot,   // [b][1024][256]
    float* __restrict__ outf){
  const int b  = blockIdx.z;
  const int m0 = blockIdx.y * 64;
  const int n0 = blockIdx.x * 64;
  const int t  = threadIdx.x;
  const int w = t >> 6, lane = t & 63, col = lane & 15, quad = lane >> 4;
  const int wm = w & 1, wn = w >> 1;
  __shared__ unsigned short As[64][40];
  __shared__ unsigned short Bs[64][40];
  f32x4 acc[2][2];
  #pragma unroll
  for (int i = 0; i < 2; ++i)
    #pragma unroll
    for (int j = 0; j < 2; ++j) acc[i][j] = (f32x4){0.f,0.f,0.f,0.f};
  const int am = t >> 2, ak = (t & 3) * 8;
  const int bn = t >> 2, bk = (t & 3) * 8;
  const int n = n0 + bn;
  const int oy = n >> 5, ox = n & 31;
  const size_t aobase = ((size_t)b * NQ + n) * KD;

  auto loadB = [&](int k0) -> uint4 {
    if (k0 < 2304){
      int tap = k0 >> 8;                     // uniform per chunk
      int ky = tap / 3, kx = tap - ky * 3;
      int iy = 2 * oy + ky - 1, ix = 2 * ox + kx - 1;
      if (((unsigned)iy < 64u) && ((unsigned)ix < 64u))
        return *(const uint4*)(h_t + ((size_t)b * NPIX + iy * 64 + ix) * CIN + (k0 & 255) + bk);
      return make_uint4(0,0,0,0);            // conv zero-pad
    }
    return *(const uint4*)(aot + aobase + (k0 - 2304) + bk);
  };

  uint4 av = *(const uint4*)(Wf + (size_t)(m0 + am) * WF_K + ak);
  uint4 bv = loadB(0);

  for (int k0 = 0; k0 < WF_K; k0 += 32){
    *(uint4*)&As[am][ak] = av;
    *(uint4*)&Bs[bn][bk] = bv;
    __syncthreads();
    if (k0 + 32 < WF_K){
      av = *(const uint4*)(Wf + (size_t)(m0 + am) * WF_K + k0 + 32 + ak);
      bv = loadB(k0 + 32);
    }
    short8 af[2], bf[2];
    af[0] = *(const short8*)&As[wm * 32 +      col][quad * 8];
    af[1] = *(const short8*)&As[wm * 32 + 16 + col][quad * 8];
    bf[0] = *(const short8*)&Bs[wn * 32 +      col][quad * 8];
    bf[1] = *(const short8*)&Bs[wn * 32 + 16 + col][quad * 8];
    #pragma unroll
    for (int i = 0; i < 2; ++i)
      #pragma unroll
      for (int j = 0; j < 2; ++j)
        acc[i][j] = __builtin_amdgcn_mfma_f32_16x16x32_bf16(bf[j], af[i], acc[i][j], 0, 0, 0);
    __syncthreads();
  }

  #pragma unroll
  for (int i = 0; i < 2; ++i){
    int co = m0 + wm * 32 + i * 16 + col;
    #pragma unroll
    for (int j = 0; j < 2; ++j){
      int nb = n0 + wn * 32 + j * 16 + quad * 4;
      float4 o;
      o.x = acc[i][j][0]; o.y = acc[i][j][1];
      o.z = acc[i][j][2]; o.w = acc[i][j][3];
      *(float4*)(outf + ((size_t)(b * COUT + co)) * NQ + nb) = o;
    }
  }
}

// ---------------------------------------------------------------------------
// attn9b: query-split flash attention, K/V shared via LDS with REGISTER
// staging (global uint4 load -> ds_write_b128; per-lane scatter, no
// global_load_lds). One block = 8 waves = 8 q-tiles (128 queries) of one bh
// slice; all waves walk the same key stream. Per 64-key step each thread
// stages exactly one 16B fragment entry into LDS frag-native layout:
//   K region [g(2)][f(2)][l(64)][8]: elem = K[64s+32g+16f+(l&15)][8*(l>>4)+j]
//   V region (+2048): elem = V^T[16f+(l&15)][64s+32g+8*(l>>4)+j]
// Staging role (w,lane): w<4 -> K (g=w>>1, f=w&1), w>=4 -> V. Both global
// src and LDS dst are contiguous 1KB per wave (coalesced / conflict-free).
// Double-buffered, 1 barrier per step. L2 traffic: 256 x 512KB = 128 MB
// (8.4x less than the key-split design that was pure-L2-BW-bound).
// Grid 256 = 1/CU; XCD swizzle keeps each bh slice in one XCD's L2.
// ---------------------------------------------------------------------------
__global__ __launch_bounds__(512) void attn9b(
    const unsigned short* __restrict__ qt,    // [bh][1024][32] (pre-scaled)
    const unsigned short* __restrict__ ktg,   // [bh][4096][32]
    const unsigned short* __restrict__ vtg,   // [bh][128][32][32] blocked V^T
    unsigned short* __restrict__ aot){        // [b][1024][256]
  __shared__ unsigned short KV[2][4096];      // [buf][K 2048 | V 2048] shorts
  const int bid = blockIdx.x;
  const int xcd = bid & 7, idx = bid >> 3;    // 256 blocks
  const int bh = xcd * 4 + (idx & 3);         // 4 bh per XCD
  const int qg = idx >> 2;                    // 0..7 (q-groups of 128)
  const int b = bh >> 3, hd = bh & 7;
  const int t = threadIdx.x;
  const int w = t >> 6, lane = t & 63, col = lane & 15, quad = lane >> 4;
  const int q = (qg * 8 + w) * 16 + col;

  short8 qf = *(const short8*)(qt + ((size_t)bh * NQ + q) * 32 + quad * 8);
  const unsigned short* kb = ktg + (size_t)bh * NK * 32;
  const unsigned short* vb = vtg + (size_t)bh * 128 * 1024;

  // staging addresses (step s adds s*2048 shorts on the global side)
  const int sg = (w & 3) >> 1, sf = w & 1;
  const size_t ksrc = (size_t)(32 * sg + 16 * sf + col) * 32 + quad * 8;
  const size_t vsrc = (size_t)sg * 1024 + (size_t)(16 * sf + col) * 32 + quad * 8;
  unsigned short* dstp = &KV[0][w * 512 + lane * 8];   // buf1 = +4096 shorts

  f32x4 O0 = {0.f,0.f,0.f,0.f}, O1 = {0.f,0.f,0.f,0.f}, l4 = {0.f,0.f,0.f,0.f};
  const short8 ones = {0x3F80,0x3F80,0x3F80,0x3F80,0x3F80,0x3F80,0x3F80,0x3F80};

  uint4 stg = (w < 4) ? *(const uint4*)(kb + ksrc)
                      : *(const uint4*)(vb + vsrc);
  *(uint4*)dstp = stg;
  __syncthreads();

  for (int s = 0; s < 64; ++s){
    const int cur = s & 1;
    uint4 nxt;
    if (s + 1 < 64){                          // issue early: latency hides
      size_t soff = (size_t)(s + 1) * 2048;
      nxt = (w < 4) ? *(const uint4*)(kb + soff + ksrc)
                    : *(const uint4*)(vb + soff + vsrc);
    }
    #pragma unroll
    for (int g = 0; g < 2; ++g){
      const unsigned short* Kp = &KV[cur][g * 1024];
      short8 kf0 = *(const short8*)(Kp +       lane * 8);
      short8 kf1 = *(const short8*)(Kp + 512 + lane * 8);
      f32x4 z = {0.f,0.f,0.f,0.f};
      f32x4 slo = __builtin_amdgcn_mfma_f32_16x16x32_bf16(kf0, qf, z, 0, 0, 0);
      f32x4 shi = __builtin_amdgcn_mfma_f32_16x16x32_bf16(kf1, qf, z, 0, 0, 0);

      unsigned x0 = cvtpk(__builtin_amdgcn_exp2f(slo[0]), __builtin_amdgcn_exp2f(slo[1]));
      unsigned x1 = cvtpk(__builtin_amdgcn_exp2f(slo[2]), __builtin_amdgcn_exp2f(slo[3]));
      unsigned y0 = cvtpk(__builtin_amdgcn_exp2f(shi[0]), __builtin_amdgcn_exp2f(shi[1]));
      unsigned y1 = cvtpk(__builtin_amdgcn_exp2f(shi[2]), __builtin_amdgcn_exp2f(shi[3]));
      asm("v_permlane32_swap_b32 %0, %1" : "+v"(x0), "+v"(y0));
      asm("v_permlane32_swap_b32 %0, %1" : "+v"(x1), "+v"(y1));
      asm("v_permlane16_swap_b32 %0, %1" : "+v"(x0), "+v"(y0));
      asm("v_permlane16_swap_b32 %0, %1" : "+v"(x1), "+v"(y1));
      unsigned f[4] = {x0, x1, y0, y1};
      short8 pf;
      memcpy(&pf, f, 16);

      const unsigned short* Vp = &KV[cur][2048 + g * 1024];
      short8 vf0 = *(const short8*)(Vp +       lane * 8);
      short8 vf1 = *(const short8*)(Vp + 512 + lane * 8);
      O0 = __builtin_amdgcn_mfma_f32_16x16x32_bf16(vf0, pf, O0, 0, 0, 0);
      O1 = __builtin_amdgcn_mfma_f32_16x16x32_bf16(vf1, pf, O1, 0, 0, 0);
      l4 = __builtin_amdgcn_mfma_f32_16x16x32_bf16(ones, pf, l4, 0, 0, 0);
    }
    if (s + 1 < 64)
      *(uint4*)(dstp + (size_t)(cur ^ 1) * 4096) = nxt;   // write-late (T14)
    __syncthreads();   // all waves done reading cur; next buf visible
  }

  // direct epilogue: each wave owns its q-tile's full softmax
  float inv = 1.0f / l4[0];
  unsigned short* dst = aot + ((size_t)(b * NQ + q)) * KD + hd * 32;
  uint2 pk;
  pk.x = pkbf(O0[0] * inv, O0[1] * inv);
  pk.y = pkbf(O0[2] * inv, O0[3] * inv);
  *(uint2*)(dst + quad * 4) = pk;
  pk.x = pkbf(O1[0] * inv, O1[1] * inv);
  pk.y = pkbf(O1[2] * inv, O1[3] * inv);
  *(uint2*)(dst + 16 + quad * 4) = pk;
}

// ---------------------------------------------------------------------------
extern "C" void kernel_launch(void* const* d_in, const int* in_sizes, int n_in,
                              void* d_out, int out_size, void* d_ws, size_t ws_size,
                              hipStream_t stream){
  const float* x   = (const float*)d_in[0];
  const float* bg  = (const float*)d_in[1];
  const float* bbt = (const float*)d_in[2];
  const float* bm  = (const float*)d_in[3];
  const float* bv  = (const float*)d_in[4];
  const float* wsh = (const float*)d_in[5];
  const float* wq  = (const float*)d_in[6];
  const float* wk  = (const float*)d_in[7];
  const float* wvv = (const float*)d_in[8];
  const float* wo  = (const float*)d_in[9];
  float* out = (float*)d_out;                 // fp32 output

  // workspace (bf16), full 4-batch K/V: 32.4 MB
  unsigned short* h_t = (unsigned short*)d_ws;                 // 4*4096*256
  unsigned short* W2  = h_t + (size_t)BB * NPIX * CIN;         // 1,507,328
  unsigned short* qt  = W2  + (WF_E + 3*65536);                // 4*8*1024*32
  unsigned short* aot = qt  + (size_t)BB * HEADS * NQ * 32;    // 4*1024*256
  unsigned short* ktg = aot + (size_t)BB * NQ * KD;            // 4*8*4096*32
  unsigned short* vtg = ktg + (size_t)BB * HEADS * NK * 32;    // 4*8*128*1024
  size_t need = ((size_t)(vtg + (size_t)BB * HEADS * 32 * NK - h_t)) * 2;
  if (ws_size < need) return;

  unsigned short* Wf   = W2;                   // [512][2560] = wsh|wo fused
  unsigned short* wq2  = W2 + WF_E;
  unsigned short* wkv2 = wq2 + 65536;          // [wk2;wv2] = [512][256]

  prep_h<<<dim3(64, 4), dim3(256), 0, stream>>>(x, bg, bbt, bm, bv, h_t);
  prep_w3<<<dim3(832), dim3(256), 0, stream>>>(wsh, wq, wk, wvv, wo, W2);
  q_gemm<<<dim3(16, 4, 4), dim3(256), 0, stream>>>(wq2, h_t, qt);
  kv_gemm<<<dim3(32, 8, 4), dim3(256), 0, stream>>>(wkv2, h_t, ktg, vtg);
  attn9b<<<dim3(256), dim3(512), 0, stream>>>(qt, ktg, vtg, aot);
  scwo_gemm<<<dim3(16, 8, 4), dim3(256), 0, stream>>>(Wf, h_t, aot, out);
}

// Round 5
// 173.911 us; speedup vs baseline: 1.1813x; 1.0099x over previous
//
#include <hip/hip_runtime.h>

// Problem constants
#define BB    4
#define CIN   256
#define NPIX  4096     // 64*64
#define COUT  512
#define KD    256      // KEY_DIM = VAL_DIM
#define HEADS 8
#define NQ    1024     // 32*32
#define NK    4096
#define EPSV  1e-5f
// 1/sqrt(32) * log2(e): scores come out in base-2 so attn uses v_exp_f32
// directly (no v_mul per element).
#define QSCALE (0.17677669529663687f * 1.4426950408889634f)

using short8 = __attribute__((ext_vector_type(8))) short;
using f32x4  = __attribute__((ext_vector_type(4))) float;

__device__ __forceinline__ float b2f(unsigned u){ return __uint_as_float(u << 16); }
__device__ __forceinline__ unsigned short f2b(float f){
  unsigned u = __float_as_uint(f);
  return (unsigned short)((u + 0x7fffu + ((u >> 16) & 1u)) >> 16);  // RNE
}
__device__ __forceinline__ float bnrelu(float xv, float inv, float mu, float bt){
  return fmaxf((xv - mu) * inv + bt, 0.0f);
}
// pack two fp32 -> bf16x2 (round-half-up): 2 add + 1 v_perm
__device__ __forceinline__ unsigned pkbf(float lo, float hi){
  unsigned a = __float_as_uint(lo) + 0x8000u;
  unsigned b = __float_as_uint(hi) + 0x8000u;
  return __builtin_amdgcn_perm(b, a, 0x07060302u);  // [hi16(b)|hi16(a)]
}
// pack two fp32 -> bf16x2 via single HW instruction (RNE)
__device__ __forceinline__ unsigned cvtpk(float lo, float hi){
  unsigned r;
  asm("v_cvt_pk_bf16_f32 %0, %1, %2" : "=v"(r) : "v"(lo), "v"(hi));
  return r;
}

#define WF_K  2560
#define WF_E  (512*2560)

// ---------------------------------------------------------------------------
// prep_all = prep_w3 (blk<832) + prep_h (blk>=832). Merged to cut one launch;
// bodies verbatim from the verified round-3 kernels.
//  prep_h: bn+relu(x) fp32 [b][c][pix] -> bf16 h_t [b][pix][c] (LDS transpose)
//  prep_w: Wf=[512][2560] (wsh tap-major | wo), then wq(*QSCALE)|wk|wv flat.
// ---------------------------------------------------------------------------
__global__ __launch_bounds__(256) void prep_all(
    const float* __restrict__ x, const float* __restrict__ gam,
    const float* __restrict__ bet, const float* __restrict__ mea,
    const float* __restrict__ var,
    const float* __restrict__ wsh, const float* __restrict__ wq,
    const float* __restrict__ wk,  const float* __restrict__ wv,
    const float* __restrict__ wo,
    unsigned short* __restrict__ h_t, unsigned short* __restrict__ W2){
  __shared__ unsigned short T[64][264];      // prep_w reuses as float R[2304]
  const int blk = blockIdx.x;
  const int t = threadIdx.x;
  if (blk < 832){
    if (blk < 512){
      float* R = (float*)&T[0][0];
      const float* src = wsh + (size_t)blk * 2304;
      #pragma unroll
      for (int i = 0; i < 9; ++i) R[i * 256 + t] = src[i * 256 + t];
      __syncthreads();
      unsigned short* dst = W2 + (size_t)blk * WF_K;
      #pragma unroll
      for (int i = 0; i < 9; ++i){
        int kp = i * 256 + t;                // k' = tap*256 + ci
        int tap = kp >> 8, ci = kp & 255;
        dst[kp] = f2b(R[ci * 9 + tap]);
      }
    } else if (blk < 704){
      int idx = (blk - 512) * 1024 + t * 4;  // [0, 196608)
      float4 v;
      if (idx < 65536){
        v = *(const float4*)(wq + idx);
        v.x *= QSCALE; v.y *= QSCALE; v.z *= QSCALE; v.w *= QSCALE;
      } else if (idx < 2*65536){ v = *(const float4*)(wk + idx - 65536);
      } else {                   v = *(const float4*)(wv + idx - 2*65536); }
      uint2 pk;
      pk.x = (unsigned)f2b(v.x) | ((unsigned)f2b(v.y) << 16);
      pk.y = (unsigned)f2b(v.z) | ((unsigned)f2b(v.w) << 16);
      *(uint2*)(W2 + WF_E + idx) = pk;
    } else {
      int idx = (blk - 704) * 1024 + t * 4;  // [0, 131072) over wo
      int m = idx >> 8, c = idx & 255;
      float4 v = *(const float4*)(wo + idx);
      uint2 pk;
      pk.x = (unsigned)f2b(v.x) | ((unsigned)f2b(v.y) << 16);
      pk.y = (unsigned)f2b(v.z) | ((unsigned)f2b(v.w) << 16);
      *(uint2*)(W2 + (size_t)m * WF_K + 2304 + c) = pk;
    }
    return;
  }
  // ---- prep_h ----
  const int lin = blk - 832;
  const int b = lin >> 6;
  const int pix0 = (lin & 63) * 64;
  const int w = t >> 6, lane = t & 63;
  for (int cc = 0; cc < 32; ++cc){
    int c0 = cc * 8 + w * 2;
    float i0 = gam[c0]   * rsqrtf(var[c0]   + EPSV), mu0 = mea[c0],   bt0 = bet[c0];
    float i1 = gam[c0+1] * rsqrtf(var[c0+1] + EPSV), mu1 = mea[c0+1], bt1 = bet[c0+1];
    float v0 = bnrelu(x[((size_t)(b*CIN + c0  ))*NPIX + pix0 + lane], i0, mu0, bt0);
    float v1 = bnrelu(x[((size_t)(b*CIN + c0+1))*NPIX + pix0 + lane], i1, mu1, bt1);
    *(unsigned*)&T[lane][c0] = pkbf(v0, v1);
  }
  __syncthreads();
  int p = t >> 2;
  unsigned short* dst = h_t + ((size_t)b * NPIX + pix0 + p) * CIN;
  #pragma unroll
  for (int i = 0; i < 8; ++i){
    int coff = i * 32 + (t & 3) * 8;
    *(uint4*)(dst + coff) = *(const uint4*)&T[p][coff];
  }
}

// ---------------------------------------------------------------------------
// qkv_gemm: y<8 -> kv_gemm body (verbatim, round-1-verified layouts:
// ktg [bh][n][32], blocked vtg [bh][kchunk][d32][k32]); y in {8,9} ->
// q_gemm body (verbatim). Merged to cut one launch. Grid (32,10,4).
// ---------------------------------------------------------------------------
__global__ __launch_bounds__(256) void qkv_gemm(
    const unsigned short* __restrict__ Wkv,   // [wk2;wv2] = [512][256]
    const unsigned short* __restrict__ Wq,    // [256][256]
    const unsigned short* __restrict__ h_t,
    unsigned short* __restrict__ ktg,
    unsigned short* __restrict__ vtg,
    unsigned short* __restrict__ qt){
  __shared__ unsigned short As[64][40];
  __shared__ unsigned short Bs[128][40];
  const int b = blockIdx.z;
  const int t = threadIdx.x;
  const int w = t >> 6, lane = t & 63, col = lane & 15, quad = lane >> 4;
  const int wm = w & 1, wn = w >> 1;

  if (blockIdx.y < 8){
    // ---- kv_gemm ----
    const int m0 = blockIdx.y * 64;
    const bool isv = m0 >= 256;
    const int n0 = blockIdx.x * 128;
    f32x4 acc[2][4];
    #pragma unroll
    for (int i = 0; i < 2; ++i)
      #pragma unroll
      for (int j = 0; j < 4; ++j) acc[i][j] = (f32x4){0.f,0.f,0.f,0.f};
    const int am = t >> 2, ak = (t & 3) * 8;
    const int bn = t >> 1, bkh = (t & 1) * 16;
    const size_t browbase = ((size_t)b * NPIX + (n0 + bn)) * CIN;

    uint4 av  = *(const uint4*)(Wkv + (size_t)(m0 + am) * 256 + ak);
    uint4 bv0 = *(const uint4*)(h_t + browbase + bkh);
    uint4 bv1 = *(const uint4*)(h_t + browbase + bkh + 8);

    for (int k0 = 0; k0 < 256; k0 += 32){
      *(uint4*)&As[am][ak]      = av;
      *(uint4*)&Bs[bn][bkh]     = bv0;
      *(uint4*)&Bs[bn][bkh + 8] = bv1;
      __syncthreads();
      if (k0 + 32 < 256){                     // prefetch next chunk
        av  = *(const uint4*)(Wkv + (size_t)(m0 + am) * 256 + k0 + 32 + ak);
        bv0 = *(const uint4*)(h_t + browbase + k0 + 32 + bkh);
        bv1 = *(const uint4*)(h_t + browbase + k0 + 32 + bkh + 8);
      }
      short8 af[2], bf[4];
      af[0] = *(const short8*)&As[wm * 32 +      col][quad * 8];
      af[1] = *(const short8*)&As[wm * 32 + 16 + col][quad * 8];
      #pragma unroll
      for (int j = 0; j < 4; ++j)
        bf[j] = *(const short8*)&Bs[wn * 64 + j * 16 + col][quad * 8];
      if (!isv){
        #pragma unroll
        for (int i = 0; i < 2; ++i)
          #pragma unroll
          for (int j = 0; j < 4; ++j)
            acc[i][j] = __builtin_amdgcn_mfma_f32_16x16x32_bf16(af[i], bf[j], acc[i][j], 0, 0, 0);
      } else {
        #pragma unroll
        for (int i = 0; i < 2; ++i)
          #pragma unroll
          for (int j = 0; j < 4; ++j)
            acc[i][j] = __builtin_amdgcn_mfma_f32_16x16x32_bf16(bf[j], af[i], acc[i][j], 0, 0, 0);
      }
      __syncthreads();
    }

    if (!isv){
      int head = (m0 + wm * 32) >> 5;
      #pragma unroll
      for (int i = 0; i < 2; ++i){
        int d0 = i * 16 + quad * 4;
        #pragma unroll
        for (int j = 0; j < 4; ++j){
          int n = n0 + wn * 64 + j * 16 + col;
          uint2 pk;
          pk.x = pkbf(acc[i][j][0], acc[i][j][1]);
          pk.y = pkbf(acc[i][j][2], acc[i][j][3]);
          *(uint2*)(ktg + ((size_t)(b * HEADS + head) * NK + n) * 32 + d0) = pk;
        }
      }
    } else {
      int head = ((m0 - 256) + wm * 32) >> 5;
      #pragma unroll
      for (int i = 0; i < 2; ++i){
        int d = i * 16 + col;
        #pragma unroll
        for (int j = 0; j < 4; ++j){
          int nb = n0 + wn * 64 + j * 16 + quad * 4;
          size_t addr = (((size_t)(b * HEADS + head) * 128 + (nb >> 5)) * 32 + d) * 32 + (nb & 31);
          uint2 pk;
          pk.x = pkbf(acc[i][j][0], acc[i][j][1]);
          pk.y = pkbf(acc[i][j][2], acc[i][j][3]);
          *(uint2*)(vtg + addr) = pk;
        }
      }
    }
    return;
  }

  // ---- q_gemm ----
  const int lin = (blockIdx.y - 8) * 32 + blockIdx.x;   // [0,64)
  const int m0 = (lin >> 4) * 64;
  const int n0 = (lin & 15) * 64;
  f32x4 acc[2][2];
  #pragma unroll
  for (int i = 0; i < 2; ++i)
    #pragma unroll
    for (int j = 0; j < 2; ++j) acc[i][j] = (f32x4){0.f,0.f,0.f,0.f};
  const int am = t >> 2, ak = (t & 3) * 8;
  const int bn = t >> 2, bk = (t & 3) * 8;
  int n = n0 + bn;
  const size_t browbase = ((size_t)b * NPIX + (((n >> 5) << 7) + ((n & 31) << 1))) * CIN;

  uint4 av = *(const uint4*)(Wq + (size_t)(m0 + am) * 256 + ak);
  uint4 bv = *(const uint4*)(h_t + browbase + bk);

  for (int k0 = 0; k0 < 256; k0 += 32){
    *(uint4*)&As[am][ak] = av;
    *(uint4*)&Bs[bn][bk] = bv;
    __syncthreads();
    if (k0 + 32 < 256){
      av = *(const uint4*)(Wq + (size_t)(m0 + am) * 256 + k0 + 32 + ak);
      bv = *(const uint4*)(h_t + browbase + k0 + 32 + bk);
    }
    short8 af[2], bf[2];
    af[0] = *(const short8*)&As[wm * 32 +      col][quad * 8];
    af[1] = *(const short8*)&As[wm * 32 + 16 + col][quad * 8];
    bf[0] = *(const short8*)&Bs[wn * 32 +      col][quad * 8];
    bf[1] = *(const short8*)&Bs[wn * 32 + 16 + col][quad * 8];
    #pragma unroll
    for (int i = 0; i < 2; ++i)
      #pragma unroll
      for (int j = 0; j < 2; ++j)
        acc[i][j] = __builtin_amdgcn_mfma_f32_16x16x32_bf16(af[i], bf[j], acc[i][j], 0, 0, 0);
    __syncthreads();
  }

  int head = (m0 + wm * 32) >> 5;
  #pragma unroll
  for (int i = 0; i < 2; ++i){
    int d0 = i * 16 + quad * 4;
    #pragma unroll
    for (int j = 0; j < 2; ++j){
      int nn = n0 + wn * 32 + j * 16 + col;
      uint2 pk;
      pk.x = pkbf(acc[i][j][0], acc[i][j][1]);
      pk.y = pkbf(acc[i][j][2], acc[i][j][3]);
      *(uint2*)(qt + ((size_t)(b * HEADS + head) * NQ + nn) * 32 + d0) = pk;
    }
  }
}

// ---------------------------------------------------------------------------
// Fused shortcut+wo GEMM, 64x64 tiles (512 blocks = 2/CU).
// C[b][512][1024] = Wf · [im2col(h_t); aot], K = 2304 + 256. fp32 out.
// ---------------------------------------------------------------------------
__global__ __launch_bounds__(256) void scwo_gemm(
    const unsigned short* __restrict__ Wf,    // [512][2560]
    const unsigned short* __restrict__ h_t,
    const unsigned short* __restrict__ aot,   // [b][1024][256]
    float* __restrict__ outf){
  const int b  = blockIdx.z;
  const int m0 = blockIdx.y * 64;
  const int n0 = blockIdx.x * 64;
  const int t  = threadIdx.x;
  const int w = t >> 6, lane = t & 63, col = lane & 15, quad = lane >> 4;
  const int wm = w & 1, wn = w >> 1;
  __shared__ unsigned short As[64][40];
  __shared__ unsigned short Bs[64][40];
  f32x4 acc[2][2];
  #pragma unroll
  for (int i = 0; i < 2; ++i)
    #pragma unroll
    for (int j = 0; j < 2; ++j) acc[i][j] = (f32x4){0.f,0.f,0.f,0.f};
  const int am = t >> 2, ak = (t & 3) * 8;
  const int bn = t >> 2, bk = (t & 3) * 8;
  const int n = n0 + bn;
  const int oy = n >> 5, ox = n & 31;
  const size_t aobase = ((size_t)b * NQ + n) * KD;

  auto loadB = [&](int k0) -> uint4 {
    if (k0 < 2304){
      int tap = k0 >> 8;                     // uniform per chunk
      int ky = tap / 3, kx = tap - ky * 3;
      int iy = 2 * oy + ky - 1, ix = 2 * ox + kx - 1;
      if (((unsigned)iy < 64u) && ((unsigned)ix < 64u))
        return *(const uint4*)(h_t + ((size_t)b * NPIX + iy * 64 + ix) * CIN + (k0 & 255) + bk);
      return make_uint4(0,0,0,0);            // conv zero-pad
    }
    return *(const uint4*)(aot + aobase + (k0 - 2304) + bk);
  };

  uint4 av = *(const uint4*)(Wf + (size_t)(m0 + am) * WF_K + ak);
  uint4 bv = loadB(0);

  for (int k0 = 0; k0 < WF_K; k0 += 32){
    *(uint4*)&As[am][ak] = av;
    *(uint4*)&Bs[bn][bk] = bv;
    __syncthreads();
    if (k0 + 32 < WF_K){
      av = *(const uint4*)(Wf + (size_t)(m0 + am) * WF_K + k0 + 32 + ak);
      bv = loadB(k0 + 32);
    }
    short8 af[2], bf[2];
    af[0] = *(const short8*)&As[wm * 32 +      col][quad * 8];
    af[1] = *(const short8*)&As[wm * 32 + 16 + col][quad * 8];
    bf[0] = *(const short8*)&Bs[wn * 32 +      col][quad * 8];
    bf[1] = *(const short8*)&Bs[wn * 32 + 16 + col][quad * 8];
    #pragma unroll
    for (int i = 0; i < 2; ++i)
      #pragma unroll
      for (int j = 0; j < 2; ++j)
        acc[i][j] = __builtin_amdgcn_mfma_f32_16x16x32_bf16(bf[j], af[i], acc[i][j], 0, 0, 0);
    __syncthreads();
  }

  #pragma unroll
  for (int i = 0; i < 2; ++i){
    int co = m0 + wm * 32 + i * 16 + col;
    #pragma unroll
    for (int j = 0; j < 2; ++j){
      int nb = n0 + wn * 32 + j * 16 + quad * 4;
      float4 o;
      o.x = acc[i][j][0]; o.y = acc[i][j][1];
      o.z = acc[i][j][2]; o.w = acc[i][j][3];
      *(float4*)(outf + ((size_t)(b * COUT + co)) * NQ + nb) = o;
    }
  }
}

// ---------------------------------------------------------------------------
// attn9b: query-split flash attention, K/V shared via LDS with REGISTER
// staging (global uint4 load -> ds_write_b128; per-lane scatter, no
// global_load_lds). One block = 8 waves = 8 q-tiles (128 queries) of one bh
// slice; all waves walk the same key stream. Per 64-key step each thread
// stages exactly one 16B fragment entry into LDS frag-native layout:
//   K region [g(2)][f(2)][l(64)][8]: elem = K[64s+32g+16f+(l&15)][8*(l>>4)+j]
//   V region (+2048): elem = V^T[16f+(l&15)][64s+32g+8*(l>>4)+j]
// Staging role (w,lane): w<4 -> K (g=w>>1, f=w&1), w>=4 -> V. Both global
// src and LDS dst are contiguous 1KB per wave (coalesced / conflict-free).
// Double-buffered, 1 barrier per step. L2 traffic: 256 x 512KB = 128 MB
// (8.4x less than the key-split design that was pure-L2-BW-bound).
// Grid 256 = 1/CU; XCD swizzle keeps each bh slice in one XCD's L2.
// (byte-exact round-3 verified version)
// ---------------------------------------------------------------------------
__global__ __launch_bounds__(512) void attn9b(
    const unsigned short* __restrict__ qt,    // [bh][1024][32] (pre-scaled)
    const unsigned short* __restrict__ ktg,   // [bh][4096][32]
    const unsigned short* __restrict__ vtg,   // [bh][128][32][32] blocked V^T
    unsigned short* __restrict__ aot){        // [b][1024][256]
  __shared__ unsigned short KV[2][4096];      // [buf][K 2048 | V 2048] shorts
  const int bid = blockIdx.x;
  const int xcd = bid & 7, idx = bid >> 3;    // 256 blocks
  const int bh = xcd * 4 + (idx & 3);         // 4 bh per XCD
  const int qg = idx >> 2;                    // 0..7 (q-groups of 128)
  const int b = bh >> 3, hd = bh & 7;
  const int t = threadIdx.x;
  const int w = t >> 6, lane = t & 63, col = lane & 15, quad = lane >> 4;
  const int q = (qg * 8 + w) * 16 + col;

  short8 qf = *(const short8*)(qt + ((size_t)bh * NQ + q) * 32 + quad * 8);
  const unsigned short* kb = ktg + (size_t)bh * NK * 32;
  const unsigned short* vb = vtg + (size_t)bh * 128 * 1024;

  // staging addresses (step s adds s*2048 shorts on the global side)
  const int sg = (w & 3) >> 1, sf = w & 1;
  const size_t ksrc = (size_t)(32 * sg + 16 * sf + col) * 32 + quad * 8;
  const size_t vsrc = (size_t)sg * 1024 + (size_t)(16 * sf + col) * 32 + quad * 8;
  unsigned short* dstp = &KV[0][w * 512 + lane * 8];   // buf1 = +4096 shorts

  f32x4 O0 = {0.f,0.f,0.f,0.f}, O1 = {0.f,0.f,0.f,0.f}, l4 = {0.f,0.f,0.f,0.f};
  const short8 ones = {0x3F80,0x3F80,0x3F80,0x3F80,0x3F80,0x3F80,0x3F80,0x3F80};

  uint4 stg = (w < 4) ? *(const uint4*)(kb + ksrc)
                      : *(const uint4*)(vb + vsrc);
  *(uint4*)dstp = stg;
  __syncthreads();

  for (int s = 0; s < 64; ++s){
    const int cur = s & 1;
    uint4 nxt;
    if (s + 1 < 64){                          // issue early: latency hides
      size_t soff = (size_t)(s + 1) * 2048;
      nxt = (w < 4) ? *(const uint4*)(kb + soff + ksrc)
                    : *(const uint4*)(vb + soff + vsrc);
    }
    #pragma unroll
    for (int g = 0; g < 2; ++g){
      const unsigned short* Kp = &KV[cur][g * 1024];
      short8 kf0 = *(const short8*)(Kp +       lane * 8);
      short8 kf1 = *(const short8*)(Kp + 512 + lane * 8);
      f32x4 z = {0.f,0.f,0.f,0.f};
      f32x4 slo = __builtin_amdgcn_mfma_f32_16x16x32_bf16(kf0, qf, z, 0, 0, 0);
      f32x4 shi = __builtin_amdgcn_mfma_f32_16x16x32_bf16(kf1, qf, z, 0, 0, 0);

      unsigned x0 = cvtpk(__builtin_amdgcn_exp2f(slo[0]), __builtin_amdgcn_exp2f(slo[1]));
      unsigned x1 = cvtpk(__builtin_amdgcn_exp2f(slo[2]), __builtin_amdgcn_exp2f(slo[3]));
      unsigned y0 = cvtpk(__builtin_amdgcn_exp2f(shi[0]), __builtin_amdgcn_exp2f(shi[1]));
      unsigned y1 = cvtpk(__builtin_amdgcn_exp2f(shi[2]), __builtin_amdgcn_exp2f(shi[3]));
      asm("v_permlane32_swap_b32 %0, %1" : "+v"(x0), "+v"(y0));
      asm("v_permlane32_swap_b32 %0, %1" : "+v"(x1), "+v"(y1));
      asm("v_permlane16_swap_b32 %0, %1" : "+v"(x0), "+v"(y0));
      asm("v_permlane16_swap_b32 %0, %1" : "+v"(x1), "+v"(y1));
      unsigned f[4] = {x0, x1, y0, y1};
      short8 pf;
      memcpy(&pf, f, 16);

      const unsigned short* Vp = &KV[cur][2048 + g * 1024];
      short8 vf0 = *(const short8*)(Vp +       lane * 8);
      short8 vf1 = *(const short8*)(Vp + 512 + lane * 8);
      O0 = __builtin_amdgcn_mfma_f32_16x16x32_bf16(vf0, pf, O0, 0, 0, 0);
      O1 = __builtin_amdgcn_mfma_f32_16x16x32_bf16(vf1, pf, O1, 0, 0, 0);
      l4 = __builtin_amdgcn_mfma_f32_16x16x32_bf16(ones, pf, l4, 0, 0, 0);
    }
    if (s + 1 < 64)
      *(uint4*)(dstp + (size_t)(cur ^ 1) * 4096) = nxt;   // write-late (T14)
    __syncthreads();   // all waves done reading cur; next buf visible
  }

  // direct epilogue: each wave owns its q-tile's full softmax
  float inv = 1.0f / l4[0];
  unsigned short* dst = aot + ((size_t)(b * NQ + q)) * KD + hd * 32;
  uint2 pk;
  pk.x = pkbf(O0[0] * inv, O0[1] * inv);
  pk.y = pkbf(O0[2] * inv, O0[3] * inv);
  *(uint2*)(dst + quad * 4) = pk;
  pk.x = pkbf(O1[0] * inv, O1[1] * inv);
  pk.y = pkbf(O1[2] * inv, O1[3] * inv);
  *(uint2*)(dst + 16 + quad * 4) = pk;
}

// ---------------------------------------------------------------------------
extern "C" void kernel_launch(void* const* d_in, const int* in_sizes, int n_in,
                              void* d_out, int out_size, void* d_ws, size_t ws_size,
                              hipStream_t stream){
  const float* x   = (const float*)d_in[0];
  const float* bg  = (const float*)d_in[1];
  const float* bbt = (const float*)d_in[2];
  const float* bm  = (const float*)d_in[3];
  const float* bv  = (const float*)d_in[4];
  const float* wsh = (const float*)d_in[5];
  const float* wq  = (const float*)d_in[6];
  const float* wk  = (const float*)d_in[7];
  const float* wvv = (const float*)d_in[8];
  const float* wo  = (const float*)d_in[9];
  float* out = (float*)d_out;                 // fp32 output

  // workspace (bf16), full 4-batch K/V: 32.4 MB
  unsigned short* h_t = (unsigned short*)d_ws;                 // 4*4096*256
  unsigned short* W2  = h_t + (size_t)BB * NPIX * CIN;         // 1,507,328
  unsigned short* qt  = W2  + (WF_E + 3*65536);                // 4*8*1024*32
  unsigned short* aot = qt  + (size_t)BB * HEADS * NQ * 32;    // 4*1024*256
  unsigned short* ktg = aot + (size_t)BB * NQ * KD;            // 4*8*4096*32
  unsigned short* vtg = ktg + (size_t)BB * HEADS * NK * 32;    // 4*8*128*1024
  size_t need = ((size_t)(vtg + (size_t)BB * HEADS * 32 * NK - h_t)) * 2;
  if (ws_size < need) return;

  unsigned short* Wf   = W2;                   // [512][2560] = wsh|wo fused
  unsigned short* wq2  = W2 + WF_E;
  unsigned short* wkv2 = wq2 + 65536;          // [wk2;wv2] = [512][256]

  prep_all<<<dim3(1088), dim3(256), 0, stream>>>(x, bg, bbt, bm, bv,
                                                 wsh, wq, wk, wvv, wo, h_t, W2);
  qkv_gemm<<<dim3(32, 10, 4), dim3(256), 0, stream>>>(wkv2, wq2, h_t, ktg, vtg, qt);
  attn9b<<<dim3(256), dim3(512), 0, stream>>>(qt, ktg, vtg, aot);
  scwo_gemm<<<dim3(16, 8, 4), dim3(256), 0, stream>>>(Wf, h_t, aot, out);
}

// Round 6
// 167.415 us; speedup vs baseline: 1.2271x; 1.0388x over previous
//
#include <hip/hip_runtime.h>

// Problem constants
#define BB    4
#define CIN   256
#define NPIX  4096     // 64*64
#define COUT  512
#define KD    256      // KEY_DIM = VAL_DIM
#define HEADS 8
#define NQ    1024     // 32*32
#define NK    4096
#define EPSV  1e-5f
// 1/sqrt(32) * log2(e): scores come out in base-2 so attn uses v_exp_f32
// directly (no v_mul per element).
#define QSCALE (0.17677669529663687f * 1.4426950408889634f)

using short8 = __attribute__((ext_vector_type(8))) short;
using f32x4  = __attribute__((ext_vector_type(4))) float;

__device__ __forceinline__ float b2f(unsigned u){ return __uint_as_float(u << 16); }
__device__ __forceinline__ unsigned short f2b(float f){
  unsigned u = __float_as_uint(f);
  return (unsigned short)((u + 0x7fffu + ((u >> 16) & 1u)) >> 16);  // RNE
}
__device__ __forceinline__ float bnrelu(float xv, float inv, float mu, float bt){
  return fmaxf((xv - mu) * inv + bt, 0.0f);
}
// pack two fp32 -> bf16x2 (round-half-up): 2 add + 1 v_perm
__device__ __forceinline__ unsigned pkbf(float lo, float hi){
  unsigned a = __float_as_uint(lo) + 0x8000u;
  unsigned b = __float_as_uint(hi) + 0x8000u;
  return __builtin_amdgcn_perm(b, a, 0x07060302u);  // [hi16(b)|hi16(a)]
}
// pack two fp32 -> bf16x2 via single HW instruction (RNE)
__device__ __forceinline__ unsigned cvtpk(float lo, float hi){
  unsigned r;
  asm("v_cvt_pk_bf16_f32 %0, %1, %2" : "=v"(r) : "v"(lo), "v"(hi));
  return r;
}

#define WF_K  2560
#define WF_E  (512*2560)

// ---------------------------------------------------------------------------
// prep_all = prep_w3 (blk<832) + prep_h (blk>=832). Merged to cut one launch;
// bodies verbatim from the verified round-3 kernels.
//  prep_h: bn+relu(x) fp32 [b][c][pix] -> bf16 h_t [b][pix][c] (LDS transpose)
//  prep_w: Wf=[512][2560] (wsh tap-major | wo), then wq(*QSCALE)|wk|wv flat.
// ---------------------------------------------------------------------------
__global__ __launch_bounds__(256) void prep_all(
    const float* __restrict__ x, const float* __restrict__ gam,
    const float* __restrict__ bet, const float* __restrict__ mea,
    const float* __restrict__ var,
    const float* __restrict__ wsh, const float* __restrict__ wq,
    const float* __restrict__ wk,  const float* __restrict__ wv,
    const float* __restrict__ wo,
    unsigned short* __restrict__ h_t, unsigned short* __restrict__ W2){
  __shared__ unsigned short T[64][264];      // prep_w reuses as float R[2304]
  const int blk = blockIdx.x;
  const int t = threadIdx.x;
  if (blk < 832){
    if (blk < 512){
      float* R = (float*)&T[0][0];
      const float* src = wsh + (size_t)blk * 2304;
      #pragma unroll
      for (int i = 0; i < 9; ++i) R[i * 256 + t] = src[i * 256 + t];
      __syncthreads();
      unsigned short* dst = W2 + (size_t)blk * WF_K;
      #pragma unroll
      for (int i = 0; i < 9; ++i){
        int kp = i * 256 + t;                // k' = tap*256 + ci
        int tap = kp >> 8, ci = kp & 255;
        dst[kp] = f2b(R[ci * 9 + tap]);
      }
    } else if (blk < 704){
      int idx = (blk - 512) * 1024 + t * 4;  // [0, 196608)
      float4 v;
      if (idx < 65536){
        v = *(const float4*)(wq + idx);
        v.x *= QSCALE; v.y *= QSCALE; v.z *= QSCALE; v.w *= QSCALE;
      } else if (idx < 2*65536){ v = *(const float4*)(wk + idx - 65536);
      } else {                   v = *(const float4*)(wv + idx - 2*65536); }
      uint2 pk;
      pk.x = (unsigned)f2b(v.x) | ((unsigned)f2b(v.y) << 16);
      pk.y = (unsigned)f2b(v.z) | ((unsigned)f2b(v.w) << 16);
      *(uint2*)(W2 + WF_E + idx) = pk;
    } else {
      int idx = (blk - 704) * 1024 + t * 4;  // [0, 131072) over wo
      int m = idx >> 8, c = idx & 255;
      float4 v = *(const float4*)(wo + idx);
      uint2 pk;
      pk.x = (unsigned)f2b(v.x) | ((unsigned)f2b(v.y) << 16);
      pk.y = (unsigned)f2b(v.z) | ((unsigned)f2b(v.w) << 16);
      *(uint2*)(W2 + (size_t)m * WF_K + 2304 + c) = pk;
    }
    return;
  }
  // ---- prep_h ----
  const int lin = blk - 832;
  const int b = lin >> 6;
  const int pix0 = (lin & 63) * 64;
  const int w = t >> 6, lane = t & 63;
  for (int cc = 0; cc < 32; ++cc){
    int c0 = cc * 8 + w * 2;
    float i0 = gam[c0]   * rsqrtf(var[c0]   + EPSV), mu0 = mea[c0],   bt0 = bet[c0];
    float i1 = gam[c0+1] * rsqrtf(var[c0+1] + EPSV), mu1 = mea[c0+1], bt1 = bet[c0+1];
    float v0 = bnrelu(x[((size_t)(b*CIN + c0  ))*NPIX + pix0 + lane], i0, mu0, bt0);
    float v1 = bnrelu(x[((size_t)(b*CIN + c0+1))*NPIX + pix0 + lane], i1, mu1, bt1);
    *(unsigned*)&T[lane][c0] = pkbf(v0, v1);
  }
  __syncthreads();
  int p = t >> 2;
  unsigned short* dst = h_t + ((size_t)b * NPIX + pix0 + p) * CIN;
  #pragma unroll
  for (int i = 0; i < 8; ++i){
    int coff = i * 32 + (t & 3) * 8;
    *(uint4*)(dst + coff) = *(const uint4*)&T[p][coff];
  }
}

// ---------------------------------------------------------------------------
// qkv_gemm: y<8 -> kv_gemm body (verbatim, round-1-verified layouts:
// ktg [bh][n][32], blocked vtg [bh][kchunk][d32][k32]); y in {8,9} ->
// q_gemm body (verbatim). Merged to cut one launch. Grid (32,10,4).
// ---------------------------------------------------------------------------
__global__ __launch_bounds__(256) void qkv_gemm(
    const unsigned short* __restrict__ Wkv,   // [wk2;wv2] = [512][256]
    const unsigned short* __restrict__ Wq,    // [256][256]
    const unsigned short* __restrict__ h_t,
    unsigned short* __restrict__ ktg,
    unsigned short* __restrict__ vtg,
    unsigned short* __restrict__ qt){
  __shared__ unsigned short As[64][40];
  __shared__ unsigned short Bs[128][40];
  const int b = blockIdx.z;
  const int t = threadIdx.x;
  const int w = t >> 6, lane = t & 63, col = lane & 15, quad = lane >> 4;
  const int wm = w & 1, wn = w >> 1;

  if (blockIdx.y < 8){
    // ---- kv_gemm ----
    const int m0 = blockIdx.y * 64;
    const bool isv = m0 >= 256;
    const int n0 = blockIdx.x * 128;
    f32x4 acc[2][4];
    #pragma unroll
    for (int i = 0; i < 2; ++i)
      #pragma unroll
      for (int j = 0; j < 4; ++j) acc[i][j] = (f32x4){0.f,0.f,0.f,0.f};
    const int am = t >> 2, ak = (t & 3) * 8;
    const int bn = t >> 1, bkh = (t & 1) * 16;
    const size_t browbase = ((size_t)b * NPIX + (n0 + bn)) * CIN;

    uint4 av  = *(const uint4*)(Wkv + (size_t)(m0 + am) * 256 + ak);
    uint4 bv0 = *(const uint4*)(h_t + browbase + bkh);
    uint4 bv1 = *(const uint4*)(h_t + browbase + bkh + 8);

    for (int k0 = 0; k0 < 256; k0 += 32){
      *(uint4*)&As[am][ak]      = av;
      *(uint4*)&Bs[bn][bkh]     = bv0;
      *(uint4*)&Bs[bn][bkh + 8] = bv1;
      __syncthreads();
      if (k0 + 32 < 256){                     // prefetch next chunk
        av  = *(const uint4*)(Wkv + (size_t)(m0 + am) * 256 + k0 + 32 + ak);
        bv0 = *(const uint4*)(h_t + browbase + k0 + 32 + bkh);
        bv1 = *(const uint4*)(h_t + browbase + k0 + 32 + bkh + 8);
      }
      short8 af[2], bf[4];
      af[0] = *(const short8*)&As[wm * 32 +      col][quad * 8];
      af[1] = *(const short8*)&As[wm * 32 + 16 + col][quad * 8];
      #pragma unroll
      for (int j = 0; j < 4; ++j)
        bf[j] = *(const short8*)&Bs[wn * 64 + j * 16 + col][quad * 8];
      if (!isv){
        #pragma unroll
        for (int i = 0; i < 2; ++i)
          #pragma unroll
          for (int j = 0; j < 4; ++j)
            acc[i][j] = __builtin_amdgcn_mfma_f32_16x16x32_bf16(af[i], bf[j], acc[i][j], 0, 0, 0);
      } else {
        #pragma unroll
        for (int i = 0; i < 2; ++i)
          #pragma unroll
          for (int j = 0; j < 4; ++j)
            acc[i][j] = __builtin_amdgcn_mfma_f32_16x16x32_bf16(bf[j], af[i], acc[i][j], 0, 0, 0);
      }
      __syncthreads();
    }

    if (!isv){
      int head = (m0 + wm * 32) >> 5;
      #pragma unroll
      for (int i = 0; i < 2; ++i){
        int d0 = i * 16 + quad * 4;
        #pragma unroll
        for (int j = 0; j < 4; ++j){
          int n = n0 + wn * 64 + j * 16 + col;
          uint2 pk;
          pk.x = pkbf(acc[i][j][0], acc[i][j][1]);
          pk.y = pkbf(acc[i][j][2], acc[i][j][3]);
          *(uint2*)(ktg + ((size_t)(b * HEADS + head) * NK + n) * 32 + d0) = pk;
        }
      }
    } else {
      int head = ((m0 - 256) + wm * 32) >> 5;
      #pragma unroll
      for (int i = 0; i < 2; ++i){
        int d = i * 16 + col;
        #pragma unroll
        for (int j = 0; j < 4; ++j){
          int nb = n0 + wn * 64 + j * 16 + quad * 4;
          size_t addr = (((size_t)(b * HEADS + head) * 128 + (nb >> 5)) * 32 + d) * 32 + (nb & 31);
          uint2 pk;
          pk.x = pkbf(acc[i][j][0], acc[i][j][1]);
          pk.y = pkbf(acc[i][j][2], acc[i][j][3]);
          *(uint2*)(vtg + addr) = pk;
        }
      }
    }
    return;
  }

  // ---- q_gemm ----
  const int lin = (blockIdx.y - 8) * 32 + blockIdx.x;   // [0,64)
  const int m0 = (lin >> 4) * 64;
  const int n0 = (lin & 15) * 64;
  f32x4 acc[2][2];
  #pragma unroll
  for (int i = 0; i < 2; ++i)
    #pragma unroll
    for (int j = 0; j < 2; ++j) acc[i][j] = (f32x4){0.f,0.f,0.f,0.f};
  const int am = t >> 2, ak = (t & 3) * 8;
  const int bn = t >> 2, bk = (t & 3) * 8;
  int n = n0 + bn;
  const size_t browbase = ((size_t)b * NPIX + (((n >> 5) << 7) + ((n & 31) << 1))) * CIN;

  uint4 av = *(const uint4*)(Wq + (size_t)(m0 + am) * 256 + ak);
  uint4 bv = *(const uint4*)(h_t + browbase + bk);

  for (int k0 = 0; k0 < 256; k0 += 32){
    *(uint4*)&As[am][ak] = av;
    *(uint4*)&Bs[bn][bk] = bv;
    __syncthreads();
    if (k0 + 32 < 256){
      av = *(const uint4*)(Wq + (size_t)(m0 + am) * 256 + k0 + 32 + ak);
      bv = *(const uint4*)(h_t + browbase + k0 + 32 + bk);
    }
    short8 af[2], bf[2];
    af[0] = *(const short8*)&As[wm * 32 +      col][quad * 8];
    af[1] = *(const short8*)&As[wm * 32 + 16 + col][quad * 8];
    bf[0] = *(const short8*)&Bs[wn * 32 +      col][quad * 8];
    bf[1] = *(const short8*)&Bs[wn * 32 + 16 + col][quad * 8];
    #pragma unroll
    for (int i = 0; i < 2; ++i)
      #pragma unroll
      for (int j = 0; j < 2; ++j)
        acc[i][j] = __builtin_amdgcn_mfma_f32_16x16x32_bf16(af[i], bf[j], acc[i][j], 0, 0, 0);
    __syncthreads();
  }

  int head = (m0 + wm * 32) >> 5;
  #pragma unroll
  for (int i = 0; i < 2; ++i){
    int d0 = i * 16 + quad * 4;
    #pragma unroll
    for (int j = 0; j < 2; ++j){
      int nn = n0 + wn * 32 + j * 16 + col;
      uint2 pk;
      pk.x = pkbf(acc[i][j][0], acc[i][j][1]);
      pk.y = pkbf(acc[i][j][2], acc[i][j][3]);
      *(uint2*)(qt + ((size_t)(b * HEADS + head) * NQ + nn) * 32 + d0) = pk;
    }
  }
}

// ---------------------------------------------------------------------------
// Fused shortcut+wo GEMM, 64x64 tiles (512 blocks = 2/CU), BK=64.
// C[b][512][1024] = Wf · [im2col(h_t); aot], K = 2304 + 256. fp32 out.
// BK=32 -> 64: halves barrier count (80 -> 40), doubles MFMA (4 -> 8) and
// ds_read work per barrier -- amortizes the fixed per-step stage+drain cost.
// Accumulation order (ascending k) unchanged -> bitwise-identical output.
// loadB still called per-32-chunk (each chunk within one conv tap).
// ---------------------------------------------------------------------------
__global__ __launch_bounds__(256) void scwo_gemm(
    const unsigned short* __restrict__ Wf,    // [512][2560]
    const unsigned short* __restrict__ h_t,
    const unsigned short* __restrict__ aot,   // [b][1024][256]
    float* __restrict__ outf){
  const int b  = blockIdx.z;
  const int m0 = blockIdx.y * 64;
  const int n0 = blockIdx.x * 64;
  const int t  = threadIdx.x;
  const int w = t >> 6, lane = t & 63, col = lane & 15, quad = lane >> 4;
  const int wm = w & 1, wn = w >> 1;
  __shared__ unsigned short As[64][72];
  __shared__ unsigned short Bs[64][72];
  f32x4 acc[2][2];
  #pragma unroll
  for (int i = 0; i < 2; ++i)
    #pragma unroll
    for (int j = 0; j < 2; ++j) acc[i][j] = (f32x4){0.f,0.f,0.f,0.f};
  const int am = t >> 2, ak = (t & 3) * 8;
  const int bn = t >> 2, bk = (t & 3) * 8;
  const int n = n0 + bn;
  const int oy = n >> 5, ox = n & 31;
  const size_t aobase = ((size_t)b * NQ + n) * KD;

  auto loadB = [&](int k0) -> uint4 {
    if (k0 < 2304){
      int tap = k0 >> 8;                     // uniform per 32-chunk
      int ky = tap / 3, kx = tap - ky * 3;
      int iy = 2 * oy + ky - 1, ix = 2 * ox + kx - 1;
      if (((unsigned)iy < 64u) && ((unsigned)ix < 64u))
        return *(const uint4*)(h_t + ((size_t)b * NPIX + iy * 64 + ix) * CIN + (k0 & 255) + bk);
      return make_uint4(0,0,0,0);            // conv zero-pad
    }
    return *(const uint4*)(aot + aobase + (k0 - 2304) + bk);
  };

  uint4 av0 = *(const uint4*)(Wf + (size_t)(m0 + am) * WF_K + ak);
  uint4 av1 = *(const uint4*)(Wf + (size_t)(m0 + am) * WF_K + 32 + ak);
  uint4 bv0 = loadB(0);
  uint4 bv1 = loadB(32);

  for (int k0 = 0; k0 < WF_K; k0 += 64){
    *(uint4*)&As[am][ak]      = av0;
    *(uint4*)&As[am][32 + ak] = av1;
    *(uint4*)&Bs[bn][bk]      = bv0;
    *(uint4*)&Bs[bn][32 + bk] = bv1;
    __syncthreads();
    if (k0 + 64 < WF_K){
      av0 = *(const uint4*)(Wf + (size_t)(m0 + am) * WF_K + k0 + 64 + ak);
      av1 = *(const uint4*)(Wf + (size_t)(m0 + am) * WF_K + k0 + 96 + ak);
      bv0 = loadB(k0 + 64);
      bv1 = loadB(k0 + 96);
    }
    #pragma unroll
    for (int h = 0; h < 2; ++h){
      short8 af[2], bf[2];
      af[0] = *(const short8*)&As[wm * 32 +      col][h * 32 + quad * 8];
      af[1] = *(const short8*)&As[wm * 32 + 16 + col][h * 32 + quad * 8];
      bf[0] = *(const short8*)&Bs[wn * 32 +      col][h * 32 + quad * 8];
      bf[1] = *(const short8*)&Bs[wn * 32 + 16 + col][h * 32 + quad * 8];
      #pragma unroll
      for (int i = 0; i < 2; ++i)
        #pragma unroll
        for (int j = 0; j < 2; ++j)
          acc[i][j] = __builtin_amdgcn_mfma_f32_16x16x32_bf16(bf[j], af[i], acc[i][j], 0, 0, 0);
    }
    __syncthreads();
  }

  #pragma unroll
  for (int i = 0; i < 2; ++i){
    int co = m0 + wm * 32 + i * 16 + col;
    #pragma unroll
    for (int j = 0; j < 2; ++j){
      int nb = n0 + wn * 32 + j * 16 + quad * 4;
      float4 o;
      o.x = acc[i][j][0]; o.y = acc[i][j][1];
      o.z = acc[i][j][2]; o.w = acc[i][j][3];
      *(float4*)(outf + ((size_t)(b * COUT + co)) * NQ + nb) = o;
    }
  }
}

// ---------------------------------------------------------------------------
// attn9b: query-split flash attention, K/V shared via LDS with REGISTER
// staging (global uint4 load -> ds_write_b128; per-lane scatter, no
// global_load_lds). One block = 8 waves = 8 q-tiles (128 queries) of one bh
// slice; all waves walk the same key stream. Per 64-key step each thread
// stages exactly one 16B fragment entry into LDS frag-native layout:
//   K region [g(2)][f(2)][l(64)][8]: elem = K[64s+32g+16f+(l&15)][8*(l>>4)+j]
//   V region (+2048): elem = V^T[16f+(l&15)][64s+32g+8*(l>>4)+j]
// Staging role (w,lane): w<4 -> K (g=w>>1, f=w&1), w>=4 -> V. Both global
// src and LDS dst are contiguous 1KB per wave (coalesced / conflict-free).
// Double-buffered, 1 barrier per step. L2 traffic: 256 x 512KB = 128 MB
// (8.4x less than the key-split design that was pure-L2-BW-bound).
// Grid 256 = 1/CU; XCD swizzle keeps each bh slice in one XCD's L2.
// (byte-exact round-3 verified version)
// ---------------------------------------------------------------------------
__global__ __launch_bounds__(512) void attn9b(
    const unsigned short* __restrict__ qt,    // [bh][1024][32] (pre-scaled)
    const unsigned short* __restrict__ ktg,   // [bh][4096][32]
    const unsigned short* __restrict__ vtg,   // [bh][128][32][32] blocked V^T
    unsigned short* __restrict__ aot){        // [b][1024][256]
  __shared__ unsigned short KV[2][4096];      // [buf][K 2048 | V 2048] shorts
  const int bid = blockIdx.x;
  const int xcd = bid & 7, idx = bid >> 3;    // 256 blocks
  const int bh = xcd * 4 + (idx & 3);         // 4 bh per XCD
  const int qg = idx >> 2;                    // 0..7 (q-groups of 128)
  const int b = bh >> 3, hd = bh & 7;
  const int t = threadIdx.x;
  const int w = t >> 6, lane = t & 63, col = lane & 15, quad = lane >> 4;
  const int q = (qg * 8 + w) * 16 + col;

  short8 qf = *(const short8*)(qt + ((size_t)bh * NQ + q) * 32 + quad * 8);
  const unsigned short* kb = ktg + (size_t)bh * NK * 32;
  const unsigned short* vb = vtg + (size_t)bh * 128 * 1024;

  // staging addresses (step s adds s*2048 shorts on the global side)
  const int sg = (w & 3) >> 1, sf = w & 1;
  const size_t ksrc = (size_t)(32 * sg + 16 * sf + col) * 32 + quad * 8;
  const size_t vsrc = (size_t)sg * 1024 + (size_t)(16 * sf + col) * 32 + quad * 8;
  unsigned short* dstp = &KV[0][w * 512 + lane * 8];   // buf1 = +4096 shorts

  f32x4 O0 = {0.f,0.f,0.f,0.f}, O1 = {0.f,0.f,0.f,0.f}, l4 = {0.f,0.f,0.f,0.f};
  const short8 ones = {0x3F80,0x3F80,0x3F80,0x3F80,0x3F80,0x3F80,0x3F80,0x3F80};

  uint4 stg = (w < 4) ? *(const uint4*)(kb + ksrc)
                      : *(const uint4*)(vb + vsrc);
  *(uint4*)dstp = stg;
  __syncthreads();

  for (int s = 0; s < 64; ++s){
    const int cur = s & 1;
    uint4 nxt;
    if (s + 1 < 64){                          // issue early: latency hides
      size_t soff = (size_t)(s + 1) * 2048;
      nxt = (w < 4) ? *(const uint4*)(kb + soff + ksrc)
                    : *(const uint4*)(vb + soff + vsrc);
    }
    #pragma unroll
    for (int g = 0; g < 2; ++g){
      const unsigned short* Kp = &KV[cur][g * 1024];
      short8 kf0 = *(const short8*)(Kp +       lane * 8);
      short8 kf1 = *(const short8*)(Kp + 512 + lane * 8);
      f32x4 z = {0.f,0.f,0.f,0.f};
      f32x4 slo = __builtin_amdgcn_mfma_f32_16x16x32_bf16(kf0, qf, z, 0, 0, 0);
      f32x4 shi = __builtin_amdgcn_mfma_f32_16x16x32_bf16(kf1, qf, z, 0, 0, 0);

      unsigned x0 = cvtpk(__builtin_amdgcn_exp2f(slo[0]), __builtin_amdgcn_exp2f(slo[1]));
      unsigned x1 = cvtpk(__builtin_amdgcn_exp2f(slo[2]), __builtin_amdgcn_exp2f(slo[3]));
      unsigned y0 = cvtpk(__builtin_amdgcn_exp2f(shi[0]), __builtin_amdgcn_exp2f(shi[1]));
      unsigned y1 = cvtpk(__builtin_amdgcn_exp2f(shi[2]), __builtin_amdgcn_exp2f(shi[3]));
      asm("v_permlane32_swap_b32 %0, %1" : "+v"(x0), "+v"(y0));
      asm("v_permlane32_swap_b32 %0, %1" : "+v"(x1), "+v"(y1));
      asm("v_permlane16_swap_b32 %0, %1" : "+v"(x0), "+v"(y0));
      asm("v_permlane16_swap_b32 %0, %1" : "+v"(x1), "+v"(y1));
      unsigned f[4] = {x0, x1, y0, y1};
      short8 pf;
      memcpy(&pf, f, 16);

      const unsigned short* Vp = &KV[cur][2048 + g * 1024];
      short8 vf0 = *(const short8*)(Vp +       lane * 8);
      short8 vf1 = *(const short8*)(Vp + 512 + lane * 8);
      O0 = __builtin_amdgcn_mfma_f32_16x16x32_bf16(vf0, pf, O0, 0, 0, 0);
      O1 = __builtin_amdgcn_mfma_f32_16x16x32_bf16(vf1, pf, O1, 0, 0, 0);
      l4 = __builtin_amdgcn_mfma_f32_16x16x32_bf16(ones, pf, l4, 0, 0, 0);
    }
    if (s + 1 < 64)
      *(uint4*)(dstp + (size_t)(cur ^ 1) * 4096) = nxt;   // write-late (T14)
    __syncthreads();   // all waves done reading cur; next buf visible
  }

  // direct epilogue: each wave owns its q-tile's full softmax
  float inv = 1.0f / l4[0];
  unsigned short* dst = aot + ((size_t)(b * NQ + q)) * KD + hd * 32;
  uint2 pk;
  pk.x = pkbf(O0[0] * inv, O0[1] * inv);
  pk.y = pkbf(O0[2] * inv, O0[3] * inv);
  *(uint2*)(dst + quad * 4) = pk;
  pk.x = pkbf(O1[0] * inv, O1[1] * inv);
  pk.y = pkbf(O1[2] * inv, O1[3] * inv);
  *(uint2*)(dst + 16 + quad * 4) = pk;
}

// ---------------------------------------------------------------------------
extern "C" void kernel_launch(void* const* d_in, const int* in_sizes, int n_in,
                              void* d_out, int out_size, void* d_ws, size_t ws_size,
                              hipStream_t stream){
  const float* x   = (const float*)d_in[0];
  const float* bg  = (const float*)d_in[1];
  const float* bbt = (const float*)d_in[2];
  const float* bm  = (const float*)d_in[3];
  const float* bv  = (const float*)d_in[4];
  const float* wsh = (const float*)d_in[5];
  const float* wq  = (const float*)d_in[6];
  const float* wk  = (const float*)d_in[7];
  const float* wvv = (const float*)d_in[8];
  const float* wo  = (const float*)d_in[9];
  float* out = (float*)d_out;                 // fp32 output

  // workspace (bf16), full 4-batch K/V: 32.4 MB
  unsigned short* h_t = (unsigned short*)d_ws;                 // 4*4096*256
  unsigned short* W2  = h_t + (size_t)BB * NPIX * CIN;         // 1,507,328
  unsigned short* qt  = W2  + (WF_E + 3*65536);                // 4*8*1024*32
  unsigned short* aot = qt  + (size_t)BB * HEADS * NQ * 32;    // 4*1024*256
  unsigned short* ktg = aot + (size_t)BB * NQ * KD;            // 4*8*4096*32
  unsigned short* vtg = ktg + (size_t)BB * HEADS * NK * 32;    // 4*8*128*1024
  size_t need = ((size_t)(vtg + (size_t)BB * HEADS * 32 * NK - h_t)) * 2;
  if (ws_size < need) return;

  unsigned short* Wf   = W2;                   // [512][2560] = wsh|wo fused
  unsigned short* wq2  = W2 + WF_E;
  unsigned short* wkv2 = wq2 + 65536;          // [wk2;wv2] = [512][256]

  prep_all<<<dim3(1088), dim3(256), 0, stream>>>(x, bg, bbt, bm, bv,
                                                 wsh, wq, wk, wvv, wo, h_t, W2);
  qkv_gemm<<<dim3(32, 10, 4), dim3(256), 0, stream>>>(wkv2, wq2, h_t, ktg, vtg, qt);
  attn9b<<<dim3(256), dim3(512), 0, stream>>>(qt, ktg, vtg, aot);
  scwo_gemm<<<dim3(16, 8, 4), dim3(256), 0, stream>>>(Wf, h_t, aot, out);
}

// Round 7
// 166.815 us; speedup vs baseline: 1.2316x; 1.0036x over previous
//
#include <hip/hip_runtime.h>

// Problem constants
#define BB    4
#define CIN   256
#define NPIX  4096     // 64*64
#define COUT  512
#define KD    256      // KEY_DIM = VAL_DIM
#define HEADS 8
#define NQ    1024     // 32*32
#define NK    4096
#define EPSV  1e-5f
// 1/sqrt(32) * log2(e): scores come out in base-2 so attn uses v_exp_f32
// directly (no v_mul per element).
#define QSCALE (0.17677669529663687f * 1.4426950408889634f)

using short8 = __attribute__((ext_vector_type(8))) short;
using f32x4  = __attribute__((ext_vector_type(4))) float;

__device__ __forceinline__ float b2f(unsigned u){ return __uint_as_float(u << 16); }
__device__ __forceinline__ unsigned short f2b(float f){
  unsigned u = __float_as_uint(f);
  return (unsigned short)((u + 0x7fffu + ((u >> 16) & 1u)) >> 16);  // RNE
}
__device__ __forceinline__ float bnrelu(float xv, float inv, float mu, float bt){
  return fmaxf((xv - mu) * inv + bt, 0.0f);
}
// pack two fp32 -> bf16x2 (round-half-up): 2 add + 1 v_perm
__device__ __forceinline__ unsigned pkbf(float lo, float hi){
  unsigned a = __float_as_uint(lo) + 0x8000u;
  unsigned b = __float_as_uint(hi) + 0x8000u;
  return __builtin_amdgcn_perm(b, a, 0x07060302u);  // [hi16(b)|hi16(a)]
}
// pack two fp32 -> bf16x2 via single HW instruction (RNE)
__device__ __forceinline__ unsigned cvtpk(float lo, float hi){
  unsigned r;
  asm("v_cvt_pk_bf16_f32 %0, %1, %2" : "=v"(r) : "v"(lo), "v"(hi));
  return r;
}

#define WF_K  2560
#define WF_E  (512*2560)

// ---------------------------------------------------------------------------
// prep_all = prep_w3 (blk<832) + prep_h (blk>=832). Merged to cut one launch;
// bodies verbatim from the verified round-3 kernels.
//  prep_h: bn+relu(x) fp32 [b][c][pix] -> bf16 h_t [b][pix][c] (LDS transpose)
//  prep_w: Wf=[512][2560] (wsh tap-major | wo), then wq(*QSCALE)|wk|wv flat.
// ---------------------------------------------------------------------------
__global__ __launch_bounds__(256) void prep_all(
    const float* __restrict__ x, const float* __restrict__ gam,
    const float* __restrict__ bet, const float* __restrict__ mea,
    const float* __restrict__ var,
    const float* __restrict__ wsh, const float* __restrict__ wq,
    const float* __restrict__ wk,  const float* __restrict__ wv,
    const float* __restrict__ wo,
    unsigned short* __restrict__ h_t, unsigned short* __restrict__ W2){
  __shared__ unsigned short T[64][264];      // prep_w reuses as float R[2304]
  const int blk = blockIdx.x;
  const int t = threadIdx.x;
  if (blk < 832){
    if (blk < 512){
      float* R = (float*)&T[0][0];
      const float* src = wsh + (size_t)blk * 2304;
      #pragma unroll
      for (int i = 0; i < 9; ++i) R[i * 256 + t] = src[i * 256 + t];
      __syncthreads();
      unsigned short* dst = W2 + (size_t)blk * WF_K;
      #pragma unroll
      for (int i = 0; i < 9; ++i){
        int kp = i * 256 + t;                // k' = tap*256 + ci
        int tap = kp >> 8, ci = kp & 255;
        dst[kp] = f2b(R[ci * 9 + tap]);
      }
    } else if (blk < 704){
      int idx = (blk - 512) * 1024 + t * 4;  // [0, 196608)
      float4 v;
      if (idx < 65536){
        v = *(const float4*)(wq + idx);
        v.x *= QSCALE; v.y *= QSCALE; v.z *= QSCALE; v.w *= QSCALE;
      } else if (idx < 2*65536){ v = *(const float4*)(wk + idx - 65536);
      } else {                   v = *(const float4*)(wv + idx - 2*65536); }
      uint2 pk;
      pk.x = (unsigned)f2b(v.x) | ((unsigned)f2b(v.y) << 16);
      pk.y = (unsigned)f2b(v.z) | ((unsigned)f2b(v.w) << 16);
      *(uint2*)(W2 + WF_E + idx) = pk;
    } else {
      int idx = (blk - 704) * 1024 + t * 4;  // [0, 131072) over wo
      int m = idx >> 8, c = idx & 255;
      float4 v = *(const float4*)(wo + idx);
      uint2 pk;
      pk.x = (unsigned)f2b(v.x) | ((unsigned)f2b(v.y) << 16);
      pk.y = (unsigned)f2b(v.z) | ((unsigned)f2b(v.w) << 16);
      *(uint2*)(W2 + (size_t)m * WF_K + 2304 + c) = pk;
    }
    return;
  }
  // ---- prep_h ----
  const int lin = blk - 832;
  const int b = lin >> 6;
  const int pix0 = (lin & 63) * 64;
  const int w = t >> 6, lane = t & 63;
  for (int cc = 0; cc < 32; ++cc){
    int c0 = cc * 8 + w * 2;
    float i0 = gam[c0]   * rsqrtf(var[c0]   + EPSV), mu0 = mea[c0],   bt0 = bet[c0];
    float i1 = gam[c0+1] * rsqrtf(var[c0+1] + EPSV), mu1 = mea[c0+1], bt1 = bet[c0+1];
    float v0 = bnrelu(x[((size_t)(b*CIN + c0  ))*NPIX + pix0 + lane], i0, mu0, bt0);
    float v1 = bnrelu(x[((size_t)(b*CIN + c0+1))*NPIX + pix0 + lane], i1, mu1, bt1);
    *(unsigned*)&T[lane][c0] = pkbf(v0, v1);
  }
  __syncthreads();
  int p = t >> 2;
  unsigned short* dst = h_t + ((size_t)b * NPIX + pix0 + p) * CIN;
  #pragma unroll
  for (int i = 0; i < 8; ++i){
    int coff = i * 32 + (t & 3) * 8;
    *(uint4*)(dst + coff) = *(const uint4*)&T[p][coff];
  }
}

// ---------------------------------------------------------------------------
// qkv_gemm: y<8 -> kv_gemm body (round-1-verified layouts: ktg [bh][n][32],
// blocked vtg [bh][kchunk][d32][k32]); y in {8,9} -> q_gemm body.
// BK 32 -> 64 this round (same verified transformation as round-6 scwo):
// halves barrier pairs (8 -> 4), doubles MFMA + ds_read per barrier.
// Accumulation order (ascending k) unchanged -> bitwise-identical output.
// Grid (32,10,4). LDS 27.6 KB; 4 blocks/CU = 110 KB (fits 160 KB).
// ---------------------------------------------------------------------------
__global__ __launch_bounds__(256) void qkv_gemm(
    const unsigned short* __restrict__ Wkv,   // [wk2;wv2] = [512][256]
    const unsigned short* __restrict__ Wq,    // [256][256]
    const unsigned short* __restrict__ h_t,
    unsigned short* __restrict__ ktg,
    unsigned short* __restrict__ vtg,
    unsigned short* __restrict__ qt){
  __shared__ unsigned short As[64][72];
  __shared__ unsigned short Bs[128][72];
  const int b = blockIdx.z;
  const int t = threadIdx.x;
  const int w = t >> 6, lane = t & 63, col = lane & 15, quad = lane >> 4;
  const int wm = w & 1, wn = w >> 1;

  if (blockIdx.y < 8){
    // ---- kv_gemm (BK=64) ----
    const int m0 = blockIdx.y * 64;
    const bool isv = m0 >= 256;
    const int n0 = blockIdx.x * 128;
    f32x4 acc[2][4];
    #pragma unroll
    for (int i = 0; i < 2; ++i)
      #pragma unroll
      for (int j = 0; j < 4; ++j) acc[i][j] = (f32x4){0.f,0.f,0.f,0.f};
    const int am = t >> 2, ak = (t & 3) * 8;
    const int bn = t >> 1, bkh = (t & 1) * 16;
    const size_t browbase = ((size_t)b * NPIX + (n0 + bn)) * CIN;

    uint4 av0 = *(const uint4*)(Wkv + (size_t)(m0 + am) * 256 + ak);
    uint4 av1 = *(const uint4*)(Wkv + (size_t)(m0 + am) * 256 + 32 + ak);
    uint4 bv0 = *(const uint4*)(h_t + browbase + bkh);
    uint4 bv1 = *(const uint4*)(h_t + browbase + bkh + 8);
    uint4 bv2 = *(const uint4*)(h_t + browbase + 32 + bkh);
    uint4 bv3 = *(const uint4*)(h_t + browbase + 32 + bkh + 8);

    for (int k0 = 0; k0 < 256; k0 += 64){
      *(uint4*)&As[am][ak]           = av0;
      *(uint4*)&As[am][32 + ak]      = av1;
      *(uint4*)&Bs[bn][bkh]          = bv0;
      *(uint4*)&Bs[bn][bkh + 8]      = bv1;
      *(uint4*)&Bs[bn][32 + bkh]     = bv2;
      *(uint4*)&Bs[bn][32 + bkh + 8] = bv3;
      __syncthreads();
      if (k0 + 64 < 256){                     // prefetch next chunk
        av0 = *(const uint4*)(Wkv + (size_t)(m0 + am) * 256 + k0 + 64 + ak);
        av1 = *(const uint4*)(Wkv + (size_t)(m0 + am) * 256 + k0 + 96 + ak);
        bv0 = *(const uint4*)(h_t + browbase + k0 + 64 + bkh);
        bv1 = *(const uint4*)(h_t + browbase + k0 + 64 + bkh + 8);
        bv2 = *(const uint4*)(h_t + browbase + k0 + 96 + bkh);
        bv3 = *(const uint4*)(h_t + browbase + k0 + 96 + bkh + 8);
      }
      #pragma unroll
      for (int h = 0; h < 2; ++h){
        short8 af[2], bf[4];
        af[0] = *(const short8*)&As[wm * 32 +      col][h * 32 + quad * 8];
        af[1] = *(const short8*)&As[wm * 32 + 16 + col][h * 32 + quad * 8];
        #pragma unroll
        for (int j = 0; j < 4; ++j)
          bf[j] = *(const short8*)&Bs[wn * 64 + j * 16 + col][h * 32 + quad * 8];
        if (!isv){
          #pragma unroll
          for (int i = 0; i < 2; ++i)
            #pragma unroll
            for (int j = 0; j < 4; ++j)
              acc[i][j] = __builtin_amdgcn_mfma_f32_16x16x32_bf16(af[i], bf[j], acc[i][j], 0, 0, 0);
        } else {
          #pragma unroll
          for (int i = 0; i < 2; ++i)
            #pragma unroll
            for (int j = 0; j < 4; ++j)
              acc[i][j] = __builtin_amdgcn_mfma_f32_16x16x32_bf16(bf[j], af[i], acc[i][j], 0, 0, 0);
        }
      }
      __syncthreads();
    }

    if (!isv){
      int head = (m0 + wm * 32) >> 5;
      #pragma unroll
      for (int i = 0; i < 2; ++i){
        int d0 = i * 16 + quad * 4;
        #pragma unroll
        for (int j = 0; j < 4; ++j){
          int n = n0 + wn * 64 + j * 16 + col;
          uint2 pk;
          pk.x = pkbf(acc[i][j][0], acc[i][j][1]);
          pk.y = pkbf(acc[i][j][2], acc[i][j][3]);
          *(uint2*)(ktg + ((size_t)(b * HEADS + head) * NK + n) * 32 + d0) = pk;
        }
      }
    } else {
      int head = ((m0 - 256) + wm * 32) >> 5;
      #pragma unroll
      for (int i = 0; i < 2; ++i){
        int d = i * 16 + col;
        #pragma unroll
        for (int j = 0; j < 4; ++j){
          int nb = n0 + wn * 64 + j * 16 + quad * 4;
          size_t addr = (((size_t)(b * HEADS + head) * 128 + (nb >> 5)) * 32 + d) * 32 + (nb & 31);
          uint2 pk;
          pk.x = pkbf(acc[i][j][0], acc[i][j][1]);
          pk.y = pkbf(acc[i][j][2], acc[i][j][3]);
          *(uint2*)(vtg + addr) = pk;
        }
      }
    }
    return;
  }

  // ---- q_gemm (BK=64) ----
  const int lin = (blockIdx.y - 8) * 32 + blockIdx.x;   // [0,64)
  const int m0 = (lin >> 4) * 64;
  const int n0 = (lin & 15) * 64;
  f32x4 acc[2][2];
  #pragma unroll
  for (int i = 0; i < 2; ++i)
    #pragma unroll
    for (int j = 0; j < 2; ++j) acc[i][j] = (f32x4){0.f,0.f,0.f,0.f};
  const int am = t >> 2, ak = (t & 3) * 8;
  const int bn = t >> 2, bk = (t & 3) * 8;
  int n = n0 + bn;
  const size_t browbase = ((size_t)b * NPIX + (((n >> 5) << 7) + ((n & 31) << 1))) * CIN;

  uint4 av0 = *(const uint4*)(Wq + (size_t)(m0 + am) * 256 + ak);
  uint4 av1 = *(const uint4*)(Wq + (size_t)(m0 + am) * 256 + 32 + ak);
  uint4 bv0 = *(const uint4*)(h_t + browbase + bk);
  uint4 bv1 = *(const uint4*)(h_t + browbase + 32 + bk);

  for (int k0 = 0; k0 < 256; k0 += 64){
    *(uint4*)&As[am][ak]      = av0;
    *(uint4*)&As[am][32 + ak] = av1;
    *(uint4*)&Bs[bn][bk]      = bv0;
    *(uint4*)&Bs[bn][32 + bk] = bv1;
    __syncthreads();
    if (k0 + 64 < 256){
      av0 = *(const uint4*)(Wq + (size_t)(m0 + am) * 256 + k0 + 64 + ak);
      av1 = *(const uint4*)(Wq + (size_t)(m0 + am) * 256 + k0 + 96 + ak);
      bv0 = *(const uint4*)(h_t + browbase + k0 + 64 + bk);
      bv1 = *(const uint4*)(h_t + browbase + k0 + 96 + bk);
    }
    #pragma unroll
    for (int h = 0; h < 2; ++h){
      short8 af[2], bf[2];
      af[0] = *(const short8*)&As[wm * 32 +      col][h * 32 + quad * 8];
      af[1] = *(const short8*)&As[wm * 32 + 16 + col][h * 32 + quad * 8];
      bf[0] = *(const short8*)&Bs[wn * 32 +      col][h * 32 + quad * 8];
      bf[1] = *(const short8*)&Bs[wn * 32 + 16 + col][h * 32 + quad * 8];
      #pragma unroll
      for (int i = 0; i < 2; ++i)
        #pragma unroll
        for (int j = 0; j < 2; ++j)
          acc[i][j] = __builtin_amdgcn_mfma_f32_16x16x32_bf16(af[i], bf[j], acc[i][j], 0, 0, 0);
    }
    __syncthreads();
  }

  int head = (m0 + wm * 32) >> 5;
  #pragma unroll
  for (int i = 0; i < 2; ++i){
    int d0 = i * 16 + quad * 4;
    #pragma unroll
    for (int j = 0; j < 2; ++j){
      int nn = n0 + wn * 32 + j * 16 + col;
      uint2 pk;
      pk.x = pkbf(acc[i][j][0], acc[i][j][1]);
      pk.y = pkbf(acc[i][j][2], acc[i][j][3]);
      *(uint2*)(qt + ((size_t)(b * HEADS + head) * NQ + nn) * 32 + d0) = pk;
    }
  }
}

// ---------------------------------------------------------------------------
// Fused shortcut+wo GEMM, 64x64 tiles (512 blocks = 2/CU), BK=64.
// C[b][512][1024] = Wf · [im2col(h_t); aot], K = 2304 + 256. fp32 out.
// (round-6 verified version, unchanged)
// ---------------------------------------------------------------------------
__global__ __launch_bounds__(256) void scwo_gemm(
    const unsigned short* __restrict__ Wf,    // [512][2560]
    const unsigned short* __restrict__ h_t,
    const unsigned short* __restrict__ aot,   // [b][1024][256]
    float* __restrict__ outf){
  const int b  = blockIdx.z;
  const int m0 = blockIdx.y * 64;
  const int n0 = blockIdx.x * 64;
  const int t  = threadIdx.x;
  const int w = t >> 6, lane = t & 63, col = lane & 15, quad = lane >> 4;
  const int wm = w & 1, wn = w >> 1;
  __shared__ unsigned short As[64][72];
  __shared__ unsigned short Bs[64][72];
  f32x4 acc[2][2];
  #pragma unroll
  for (int i = 0; i < 2; ++i)
    #pragma unroll
    for (int j = 0; j < 2; ++j) acc[i][j] = (f32x4){0.f,0.f,0.f,0.f};
  const int am = t >> 2, ak = (t & 3) * 8;
  const int bn = t >> 2, bk = (t & 3) * 8;
  const int n = n0 + bn;
  const int oy = n >> 5, ox = n & 31;
  const size_t aobase = ((size_t)b * NQ + n) * KD;

  auto loadB = [&](int k0) -> uint4 {
    if (k0 < 2304){
      int tap = k0 >> 8;                     // uniform per 32-chunk
      int ky = tap / 3, kx = tap - ky * 3;
      int iy = 2 * oy + ky - 1, ix = 2 * ox + kx - 1;
      if (((unsigned)iy < 64u) && ((unsigned)ix < 64u))
        return *(const uint4*)(h_t + ((size_t)b * NPIX + iy * 64 + ix) * CIN + (k0 & 255) + bk);
      return make_uint4(0,0,0,0);            // conv zero-pad
    }
    return *(const uint4*)(aot + aobase + (k0 - 2304) + bk);
  };

  uint4 av0 = *(const uint4*)(Wf + (size_t)(m0 + am) * WF_K + ak);
  uint4 av1 = *(const uint4*)(Wf + (size_t)(m0 + am) * WF_K + 32 + ak);
  uint4 bv0 = loadB(0);
  uint4 bv1 = loadB(32);

  for (int k0 = 0; k0 < WF_K; k0 += 64){
    *(uint4*)&As[am][ak]      = av0;
    *(uint4*)&As[am][32 + ak] = av1;
    *(uint4*)&Bs[bn][bk]      = bv0;
    *(uint4*)&Bs[bn][32 + bk] = bv1;
    __syncthreads();
    if (k0 + 64 < WF_K){
      av0 = *(const uint4*)(Wf + (size_t)(m0 + am) * WF_K + k0 + 64 + ak);
      av1 = *(const uint4*)(Wf + (size_t)(m0 + am) * WF_K + k0 + 96 + ak);
      bv0 = loadB(k0 + 64);
      bv1 = loadB(k0 + 96);
    }
    #pragma unroll
    for (int h = 0; h < 2; ++h){
      short8 af[2], bf[2];
      af[0] = *(const short8*)&As[wm * 32 +      col][h * 32 + quad * 8];
      af[1] = *(const short8*)&As[wm * 32 + 16 + col][h * 32 + quad * 8];
      bf[0] = *(const short8*)&Bs[wn * 32 +      col][h * 32 + quad * 8];
      bf[1] = *(const short8*)&Bs[wn * 32 + 16 + col][h * 32 + quad * 8];
      #pragma unroll
      for (int i = 0; i < 2; ++i)
        #pragma unroll
        for (int j = 0; j < 2; ++j)
          acc[i][j] = __builtin_amdgcn_mfma_f32_16x16x32_bf16(bf[j], af[i], acc[i][j], 0, 0, 0);
    }
    __syncthreads();
  }

  #pragma unroll
  for (int i = 0; i < 2; ++i){
    int co = m0 + wm * 32 + i * 16 + col;
    #pragma unroll
    for (int j = 0; j < 2; ++j){
      int nb = n0 + wn * 32 + j * 16 + quad * 4;
      float4 o;
      o.x = acc[i][j][0]; o.y = acc[i][j][1];
      o.z = acc[i][j][2]; o.w = acc[i][j][3];
      *(float4*)(outf + ((size_t)(b * COUT + co)) * NQ + nb) = o;
    }
  }
}

// ---------------------------------------------------------------------------
// attn9c = attn9b with 128-key steps (32 barriers instead of 64).
// Same 8-wave query-split, same per-g compute body (verbatim), same
// staging role formulas. LDS buffer: [K 4096 | V 4096] shorts, layout
// [half(2)][g(2)][f(2)][l][8] per region -> compute strides unchanged
// (Kp = gg*1024, Vp = 4096 + gg*1024, gg = half*2+g, keys ascending).
// Each thread stages 2 entries/step: entry2 = entry1 + 2048 shorts on BOTH
// global and LDS sides (K: +64 keys; V: +2 chunks -- both = 2048 shorts).
// Global step stride = 4096 shorts for both K and V. Double-buffered
// (2 x 16 KB = 32 KB), issue-early / write-late (T14), 1 barrier per step.
// ---------------------------------------------------------------------------
__global__ __launch_bounds__(512) void attn9c(
    const unsigned short* __restrict__ qt,    // [bh][1024][32] (pre-scaled)
    const unsigned short* __restrict__ ktg,   // [bh][4096][32]
    const unsigned short* __restrict__ vtg,   // [bh][128][32][32] blocked V^T
    unsigned short* __restrict__ aot){        // [b][1024][256]
  __shared__ unsigned short KV[2][8192];      // [buf][K 4096 | V 4096] shorts
  const int bid = blockIdx.x;
  const int xcd = bid & 7, idx = bid >> 3;    // 256 blocks
  const int bh = xcd * 4 + (idx & 3);         // 4 bh per XCD
  const int qg = idx >> 2;                    // 0..7 (q-groups of 128)
  const int b = bh >> 3, hd = bh & 7;
  const int t = threadIdx.x;
  const int w = t >> 6, lane = t & 63, col = lane & 15, quad = lane >> 4;
  const int q = (qg * 8 + w) * 16 + col;

  short8 qf = *(const short8*)(qt + ((size_t)bh * NQ + q) * 32 + quad * 8);
  const unsigned short* kb = ktg + (size_t)bh * NK * 32;
  const unsigned short* vb = vtg + (size_t)bh * 128 * 1024;

  // staging addresses (step s adds s*4096 shorts on the global side)
  const int sg = (w & 3) >> 1, sf = w & 1;
  const size_t ksrc = (size_t)(32 * sg + 16 * sf + col) * 32 + quad * 8;
  const size_t vsrc = (size_t)sg * 1024 + (size_t)(16 * sf + col) * 32 + quad * 8;
  const unsigned short* sb = (w < 4) ? kb + ksrc : vb + vsrc;
  unsigned short* ddst = &KV[0][w * 512 + lane * 8 + ((w < 4) ? 0 : 2048)];

  f32x4 O0 = {0.f,0.f,0.f,0.f}, O1 = {0.f,0.f,0.f,0.f}, l4 = {0.f,0.f,0.f,0.f};
  const short8 ones = {0x3F80,0x3F80,0x3F80,0x3F80,0x3F80,0x3F80,0x3F80,0x3F80};

  *(uint4*)ddst          = *(const uint4*)sb;
  *(uint4*)(ddst + 2048) = *(const uint4*)(sb + 2048);
  __syncthreads();

  for (int s = 0; s < 32; ++s){
    const int cur = s & 1;
    uint4 n1, n2;
    if (s + 1 < 32){                          // issue early: latency hides
      size_t soff = (size_t)(s + 1) * 4096;
      n1 = *(const uint4*)(sb + soff);
      n2 = *(const uint4*)(sb + soff + 2048);
    }
    #pragma unroll
    for (int g = 0; g < 4; ++g){
      const unsigned short* Kp = &KV[cur][g * 1024];
      short8 kf0 = *(const short8*)(Kp +       lane * 8);
      short8 kf1 = *(const short8*)(Kp + 512 + lane * 8);
      f32x4 z = {0.f,0.f,0.f,0.f};
      f32x4 slo = __builtin_amdgcn_mfma_f32_16x16x32_bf16(kf0, qf, z, 0, 0, 0);
      f32x4 shi = __builtin_amdgcn_mfma_f32_16x16x32_bf16(kf1, qf, z, 0, 0, 0);

      unsigned x0 = cvtpk(__builtin_amdgcn_exp2f(slo[0]), __builtin_amdgcn_exp2f(slo[1]));
      unsigned x1 = cvtpk(__builtin_amdgcn_exp2f(slo[2]), __builtin_amdgcn_exp2f(slo[3]));
      unsigned y0 = cvtpk(__builtin_amdgcn_exp2f(shi[0]), __builtin_amdgcn_exp2f(shi[1]));
      unsigned y1 = cvtpk(__builtin_amdgcn_exp2f(shi[2]), __builtin_amdgcn_exp2f(shi[3]));
      asm("v_permlane32_swap_b32 %0, %1" : "+v"(x0), "+v"(y0));
      asm("v_permlane32_swap_b32 %0, %1" : "+v"(x1), "+v"(y1));
      asm("v_permlane16_swap_b32 %0, %1" : "+v"(x0), "+v"(y0));
      asm("v_permlane16_swap_b32 %0, %1" : "+v"(x1), "+v"(y1));
      unsigned f[4] = {x0, x1, y0, y1};
      short8 pf;
      memcpy(&pf, f, 16);

      const unsigned short* Vp = &KV[cur][4096 + g * 1024];
      short8 vf0 = *(const short8*)(Vp +       lane * 8);
      short8 vf1 = *(const short8*)(Vp + 512 + lane * 8);
      O0 = __builtin_amdgcn_mfma_f32_16x16x32_bf16(vf0, pf, O0, 0, 0, 0);
      O1 = __builtin_amdgcn_mfma_f32_16x16x32_bf16(vf1, pf, O1, 0, 0, 0);
      l4 = __builtin_amdgcn_mfma_f32_16x16x32_bf16(ones, pf, l4, 0, 0, 0);
    }
    if (s + 1 < 32){
      *(uint4*)(ddst + (size_t)(cur ^ 1) * 8192)        = n1;   // write-late
      *(uint4*)(ddst + 2048 + (size_t)(cur ^ 1) * 8192) = n2;
    }
    __syncthreads();   // all waves done reading cur; next buf visible
  }

  // direct epilogue: each wave owns its q-tile's full softmax
  float inv = 1.0f / l4[0];
  unsigned short* dst = aot + ((size_t)(b * NQ + q)) * KD + hd * 32;
  uint2 pk;
  pk.x = pkbf(O0[0] * inv, O0[1] * inv);
  pk.y = pkbf(O0[2] * inv, O0[3] * inv);
  *(uint2*)(dst + quad * 4) = pk;
  pk.x = pkbf(O1[0] * inv, O1[1] * inv);
  pk.y = pkbf(O1[2] * inv, O1[3] * inv);
  *(uint2*)(dst + 16 + quad * 4) = pk;
}

// ---------------------------------------------------------------------------
extern "C" void kernel_launch(void* const* d_in, const int* in_sizes, int n_in,
                              void* d_out, int out_size, void* d_ws, size_t ws_size,
                              hipStream_t stream){
  const float* x   = (const float*)d_in[0];
  const float* bg  = (const float*)d_in[1];
  const float* bbt = (const float*)d_in[2];
  const float* bm  = (const float*)d_in[3];
  const float* bv  = (const float*)d_in[4];
  const float* wsh = (const float*)d_in[5];
  const float* wq  = (const float*)d_in[6];
  const float* wk  = (const float*)d_in[7];
  const float* wvv = (const float*)d_in[8];
  const float* wo  = (const float*)d_in[9];
  float* out = (float*)d_out;                 // fp32 output

  // workspace (bf16), full 4-batch K/V: 32.4 MB
  unsigned short* h_t = (unsigned short*)d_ws;                 // 4*4096*256
  unsigned short* W2  = h_t + (size_t)BB * NPIX * CIN;         // 1,507,328
  unsigned short* qt  = W2  + (WF_E + 3*65536);                // 4*8*1024*32
  unsigned short* aot = qt  + (size_t)BB * HEADS * NQ * 32;    // 4*1024*256
  unsigned short* ktg = aot + (size_t)BB * NQ * KD;            // 4*8*4096*32
  unsigned short* vtg = ktg + (size_t)BB * HEADS * NK * 32;    // 4*8*128*1024
  size_t need = ((size_t)(vtg + (size_t)BB * HEADS * 32 * NK - h_t)) * 2;
  if (ws_size < need) return;

  unsigned short* Wf   = W2;                   // [512][2560] = wsh|wo fused
  unsigned short* wq2  = W2 + WF_E;
  unsigned short* wkv2 = wq2 + 65536;          // [wk2;wv2] = [512][256]

  prep_all<<<dim3(1088), dim3(256), 0, stream>>>(x, bg, bbt, bm, bv,
                                                 wsh, wq, wk, wvv, wo, h_t, W2);
  qkv_gemm<<<dim3(32, 10, 4), dim3(256), 0, stream>>>(wkv2, wq2, h_t, ktg, vtg, qt);
  attn9c<<<dim3(256), dim3(512), 0, stream>>>(qt, ktg, vtg, aot);
  scwo_gemm<<<dim3(16, 8, 4), dim3(256), 0, stream>>>(Wf, h_t, aot, out);
}